// Round 15
// baseline (1420.142 us; speedup 1.0000x reference)
//
#include <hip/hip_runtime.h>

#define Nn 50000
#define Ee 800000
#define STEPSn 6
#define NP 49  // ceil(Nn/1024)

typedef _Float16 half8 __attribute__((ext_vector_type(8)));
typedef _Float16 half4v __attribute__((ext_vector_type(4)));
typedef float floatx4 __attribute__((ext_vector_type(4)));

typedef __attribute__((address_space(1))) void gvoid_t;
typedef __attribute__((address_space(3))) void svoid_t;

__device__ __forceinline__ float leakyf(float v) { return v > 0.f ? v : 0.2f * v; }

__device__ __forceinline__ void gload16(const void* g, void* l) {
    __builtin_amdgcn_global_load_lds((const gvoid_t*)g, (svoid_t*)l, 16, 0, 0);
}

// DPP cross-lane read: dst lane i = src lane per CTRL (quad_perm / row_ror)
template <int CTRL>
__device__ __forceinline__ float dppf(float v) {
    return __int_as_float(__builtin_amdgcn_update_dpp(
        0, __float_as_int(v), CTRL, 0xF, 0xF, true));
}

// fused broadcast-accumulate: one asm block, fixed internal order.
// s_nop 1 covers the VALU-write -> DPP-read hazard on W at block entry;
// W4's intrinsic mov_dpp is 5+ instructions before its first DPP read.
#define FMAC_DPP_GROUP(A0, A1, A2, A3, A4, A5, A6, A7, W, W4, MSG)                         \
    asm volatile(                                                                          \
        "s_nop 1\n\t"                                                                      \
        "v_fmac_f32_dpp %0, %8, %10 quad_perm:[0,0,0,0] row_mask:0xf bank_mask:0xf\n\t"    \
        "v_fmac_f32_dpp %1, %8, %10 quad_perm:[1,1,1,1] row_mask:0xf bank_mask:0xf\n\t"    \
        "v_fmac_f32_dpp %2, %8, %10 quad_perm:[2,2,2,2] row_mask:0xf bank_mask:0xf\n\t"    \
        "v_fmac_f32_dpp %3, %8, %10 quad_perm:[3,3,3,3] row_mask:0xf bank_mask:0xf\n\t"    \
        "v_fmac_f32_dpp %4, %9, %10 quad_perm:[0,0,0,0] row_mask:0xf bank_mask:0xf\n\t"    \
        "v_fmac_f32_dpp %5, %9, %10 quad_perm:[1,1,1,1] row_mask:0xf bank_mask:0xf\n\t"    \
        "v_fmac_f32_dpp %6, %9, %10 quad_perm:[2,2,2,2] row_mask:0xf bank_mask:0xf\n\t"    \
        "v_fmac_f32_dpp %7, %9, %10 quad_perm:[3,3,3,3] row_mask:0xf bank_mask:0xf"        \
        : "+v"(A0), "+v"(A1), "+v"(A2), "+v"(A3),                                          \
          "+v"(A4), "+v"(A5), "+v"(A6), "+v"(A7)                                           \
        : "v"(W), "v"(W4), "v"(MSG))

// ---------------- CSR build ----------------
__global__ void k_count(const int* __restrict__ dst, int* __restrict__ cnt) {
    int e = blockIdx.x * 256 + threadIdx.x;
    if (e < Ee) atomicAdd(&cnt[dst[e]], 1);
}

__global__ __launch_bounds__(256) void k_scan1(const int* __restrict__ cnt,
                                               int* __restrict__ part) {
    int b = blockIdx.x, t = threadIdx.x;
    int s = 0;
#pragma unroll
    for (int j = 0; j < 4; ++j) {
        int idx = b * 1024 + j * 256 + t;
        if (idx < Nn) s += cnt[idx];
    }
#pragma unroll
    for (int d = 1; d < 64; d <<= 1) s += __shfl_xor(s, d);
    __shared__ int ws[4];
    if ((t & 63) == 0) ws[t >> 6] = s;
    __syncthreads();
    if (t == 0) part[b] = ws[0] + ws[1] + ws[2] + ws[3];
}

__global__ void k_scan2(const int* __restrict__ part, int* __restrict__ pref,
                        int* __restrict__ offN) {
    int t = threadIdx.x;  // 64
    int v = (t < NP) ? part[t] : 0;
    int p = v;
#pragma unroll
    for (int d = 1; d < 64; d <<= 1) {
        int u = __shfl_up(p, d);
        if (t >= d) p += u;
    }
    if (t < NP) pref[t] = p - v;
    if (t == 63) offN[0] = p;
}

__global__ __launch_bounds__(256) void k_scan3(const int* __restrict__ cnt,
                                               const int* __restrict__ pref,
                                               int* __restrict__ off) {
    __shared__ int wsum[4];
    int b = blockIdx.x, t = threadIdx.x;
    int base = b * 1024;
    int v[4];
    int s = 0;
#pragma unroll
    for (int j = 0; j < 4; ++j) {
        int idx = base + t * 4 + j;
        v[j] = (idx < Nn) ? cnt[idx] : 0;
        s += v[j];
    }
    int lane = t & 63, w = t >> 6;
    int ps = s;
#pragma unroll
    for (int d = 1; d < 64; d <<= 1) {
        int u = __shfl_up(ps, d);
        if (lane >= d) ps += u;
    }
    if (lane == 63) wsum[w] = ps;
    __syncthreads();
    int woff = 0;
    for (int i = 0; i < w; ++i) woff += wsum[i];
    int ex = pref[b] + woff + ps - s;
#pragma unroll
    for (int j = 0; j < 4; ++j) {
        int idx = base + t * 4 + j;
        if (idx < Nn) off[idx] = ex;
        ex += v[j];
    }
}

// fill CSR slots: packed (src | lt<<20, bitcast(edge_attr)) per slot
__global__ void k_fill(const int* __restrict__ src, const int* __restrict__ dst,
                       const float* __restrict__ edge_attr, const int* __restrict__ link_type,
                       const int* __restrict__ off, int* __restrict__ cur,
                       int2* __restrict__ edata) {
    int e = blockIdx.x * 256 + threadIdx.x;
    if (e >= Ee) return;
    int d = dst[e];
    int slot = off[d] + atomicAdd(&cur[d], 1);
    edata[slot] = make_int2(src[e] | (link_type[e] << 20), __float_as_int(edge_attr[e]));
}

// ---------------- tiny per-launch constants ----------------
// C layout: [0:8] attP, [8:16] attM, [16:40] etA (3x8), [40:72] linP, [72:104] linM
__global__ void k_const(const float* __restrict__ Et, const float* __restrict__ Wea,
                        const float* __restrict__ Watt, const float* __restrict__ Wlin,
                        float* __restrict__ C) {
    __shared__ float u[50], v[50];
    int t = threadIdx.x;
    if (t < 50) {
        float w = Wea[t];
        u[t] = w * (w > 0.f ? 1.f : 0.2f);
        v[t] = w * (w < 0.f ? 1.f : 0.2f);
    }
    __syncthreads();
    if (t < 8) {
        float a = 0.f, b = 0.f;
        for (int j = 0; j < 50; ++j) {
            float w = Watt[(74 + j) * 8 + t];
            a += u[j] * w;
            b += v[j] * w;
        }
        C[t] = a;
        C[8 + t] = b;
    } else if (t < 32) {
        int lt = (t - 8) >> 3, h = (t - 8) & 7;
        float a = 0.f;
        for (int j = 0; j < 10; ++j) a += leakyf(Et[lt * 10 + j]) * Watt[(64 + j) * 8 + h];
        C[16 + (t - 8)] = a;
    } else if (t < 64) {
        int c = t - 32;
        float a = 0.f, b = 0.f;
        for (int j = 0; j < 50; ++j) {
            float w = Wlin[(32 + j) * 32 + c];
            a += u[j] * w;
            b += v[j] * w;
        }
        C[40 + c] = a;
        C[72 + c] = b;
    }
}

// ---------------- combined node-proj weights: Wcmb[128][256] fp16, bcmb[96] ----------
__global__ void k_comb(const float* __restrict__ Wh, const float* __restrict__ bh,
                       const float* __restrict__ Watt, const float* __restrict__ Wlin,
                       _Float16* __restrict__ Wcmb, float* __restrict__ bcmb) {
    int n = blockIdx.x;   // 0..127
    int k = threadIdx.x;  // 0..255
    if (n >= 96) {
        Wcmb[n * 256 + k] = (_Float16)0.f;
        return;
    }
    int ty = n / 48, c = n % 48;
    float a = 0.f;
    for (int kk = 0; kk < 32; ++kk) {
        float wsel;
        if (c < 32) wsel = Wlin[kk * 32 + c];
        else if (c < 40) wsel = Watt[kk * 8 + (c - 32)];
        else wsel = Watt[(32 + kk) * 8 + (c - 40)];
        a += Wh[ty * 8192 + k * 32 + kk] * wsel;
    }
    Wcmb[n * 256 + k] = (_Float16)a;
    if (k == 0) {
        float b = 0.f;
        for (int kk = 0; kk < 32; ++kk) {
            float wsel;
            if (c < 32) wsel = Wlin[kk * 32 + c];
            else if (c < 40) wsel = Watt[kk * 8 + (c - 32)];
            else wsel = Watt[(32 + kk) * 8 + (c - 40)];
            b += bh[ty * 32 + kk] * wsel;
        }
        bcmb[n] = b;
    }
}

__global__ void k_cvt(const float* __restrict__ x, _Float16* __restrict__ mh) {
    long i = ((long)blockIdx.x * 256 + threadIdx.x) * 4;
    if (i < (long)Nn * 256) {
        float4 v = *(const float4*)(x + i);
        half4v h;
        h[0] = (_Float16)v.x; h[1] = (_Float16)v.y;
        h[2] = (_Float16)v.z; h[3] = (_Float16)v.w;
        *(half4v*)(mh + i) = h;
    }
}

// ---------------- tiled weight transpose+convert: W [K][NN] fp32 -> WT [NN][K] fp16 ----
__global__ __launch_bounds__(256) void k_wtrans(const float* __restrict__ W,
                                                _Float16* __restrict__ WT,
                                                int K, int NN) {
    __shared__ float tile[64][65];
    int nk = K >> 6, nn = NN >> 6;
    int b = blockIdx.x;
    int s = b / (nk * nn);
    int r = b % (nk * nn);
    int kt = r / nn, nt = r % nn;
    const float* Ws = W + (long)s * K * NN;
    _Float16* WTs = WT + (long)s * K * NN;
    int lrow = threadIdx.x >> 6, lcol = threadIdx.x & 63;
#pragma unroll
    for (int i = 0; i < 16; ++i) {
        int row = i * 4 + lrow;
        tile[row][lcol] = Ws[(long)(kt * 64 + row) * NN + nt * 64 + lcol];
    }
    __syncthreads();
#pragma unroll
    for (int i = 0; i < 16; ++i) {
        int row = i * 4 + lrow;  // n index
        WTs[(long)(nt * 64 + row) * K + kt * 64 + lcol] = (_Float16)tile[lcol][row];
    }
}

// ---------------- node projections via MFMA: mh[M,256] @ Wcmb[128,256]^T ------------
__global__ __launch_bounds__(256) void k_node_proj2(
    const _Float16* __restrict__ mh, const int* __restrict__ node_type,
    const _Float16* __restrict__ Wcmb, const float* __restrict__ bcmb,
    float* __restrict__ adst, float* __restrict__ asrc,
    _Float16* __restrict__ xlin, int M) {
    __shared__ _Float16 sA[128 * 64];
    __shared__ _Float16 sB[128 * 64];
    __shared__ float sEpi[128][100];
    const int rowBase = blockIdx.x * 128;
    const int tid = threadIdx.x, wid = tid >> 6, lane = tid & 63;
    const int wm = (wid >> 1) * 64, wn = (wid & 1) * 64;

    floatx4 acc[4][4];
    floatx4 zz = {0.f, 0.f, 0.f, 0.f};
#pragma unroll
    for (int i = 0; i < 4; ++i)
#pragma unroll
        for (int j = 0; j < 4; ++j) acc[i][j] = zz;

    for (int k0 = 0; k0 < 256; k0 += 64) {
#pragma unroll
        for (int it = 0; it < 4; ++it) {
            int Ci = it * 256 + tid;
            int row = Ci >> 3, ch = Ci & 7;
            int gr = rowBase + row;
            if (gr > M - 1) gr = M - 1;
            gload16(mh + (long)gr * 256 + k0 + ((ch ^ (row & 7)) * 8),
                    &sA[(it * 256 + wid * 64) * 8]);
        }
#pragma unroll
        for (int it = 0; it < 4; ++it) {
            int Ci = it * 256 + tid;
            int row = Ci >> 3, ch = Ci & 7;
            gload16(Wcmb + (long)row * 256 + k0 + ((ch ^ (row & 7)) * 8),
                    &sB[(it * 256 + wid * 64) * 8]);
        }
        __syncthreads();
#pragma unroll
        for (int kk = 0; kk < 2; ++kk) {
            half8 af[4], bf[4];
#pragma unroll
            for (int i = 0; i < 4; ++i) {
                int row = wm + i * 16 + (lane & 15);
                int ch = (kk * 4 + (lane >> 4)) ^ (row & 7);
                af[i] = *(const half8*)&sA[row * 64 + ch * 8];
            }
#pragma unroll
            for (int j = 0; j < 4; ++j) {
                int row = wn + j * 16 + (lane & 15);
                int ch = (kk * 4 + (lane >> 4)) ^ (row & 7);
                bf[j] = *(const half8*)&sB[row * 64 + ch * 8];
            }
#pragma unroll
            for (int i = 0; i < 4; ++i)
#pragma unroll
                for (int j = 0; j < 4; ++j)
                    acc[i][j] = __builtin_amdgcn_mfma_f32_16x16x32_f16(af[i], bf[j], acc[i][j], 0, 0, 0);
        }
        __syncthreads();
    }
#pragma unroll
    for (int i = 0; i < 4; ++i)
#pragma unroll
        for (int j = 0; j < 4; ++j) {
            int col = wn + j * 16 + (lane & 15);
            if (col < 96) {
#pragma unroll
                for (int q = 0; q < 4; ++q)
                    sEpi[wm + i * 16 + (lane >> 4) * 4 + q][col] = acc[i][j][q];
            }
        }
    __syncthreads();
    for (int idx = tid; idx < 128 * 32; idx += 256) {
        int r = idx >> 5, c = idx & 31;
        int gr = rowBase + r;
        if (gr < M) {
            int ty = (node_type[gr] != 0) ? 1 : 0;
            int sc = ty * 48 + c;
            xlin[(long)gr * 32 + c] = (_Float16)(sEpi[r][sc] + bcmb[sc]);
        }
    }
    for (int idx = tid; idx < 128 * 8; idx += 256) {
        int r = idx >> 3, hh = idx & 7;
        int gr = rowBase + r;
        if (gr < M) {
            int ty = (node_type[gr] != 0) ? 1 : 0;
            adst[(long)gr * 8 + hh] = sEpi[r][ty * 48 + 32 + hh] + bcmb[ty * 48 + 32 + hh];
            asrc[(long)gr * 8 + hh] = sEpi[r][ty * 48 + 40 + hh] + bcmb[ty * 48 + 40 + hh];
        }
    }
}

// ---------------- edge aggregation + LN1 (one wave/node; fused fmac_dpp; 4-edge pipe) -
__global__ __launch_bounds__(256) void k_edge_ln1(
    const int* __restrict__ off, const int2* __restrict__ edata,
    const float* __restrict__ C,
    const float* __restrict__ adst, const float* __restrict__ asrc,
    const _Float16* __restrict__ xlin, const _Float16* __restrict__ mres,
    const float* __restrict__ g1, const float* __restrict__ b1,
    _Float16* __restrict__ m1h) {
    __shared__ float sC[104];
    if (threadIdx.x < 104) sC[threadIdx.x] = C[threadIdx.x];
    __syncthreads();
    int n = blockIdx.x * 4 + (threadIdx.x >> 6);
    int lane = threadIdx.x & 63;
    long base = off[n];
    int deg = off[n + 1] - (int)base;
    int h = lane & 7;
    int hv = lane >> 5, lc = lane & 31;
    float adst_h = adst[(long)n * 8 + h];
    float linP = sC[40 + lc], linM = sC[72 + lc];
    float ssum = 0.f;
    float acc[8] = {0.f, 0.f, 0.f, 0.f, 0.f, 0.f, 0.f, 0.f};

#define ELOAD(IDX, ED, AS, XL)                                  \
    {                                                           \
        int ci_ = (IDX) < deg ? (IDX) : deg - 1;                \
        long ei_ = base + ci_;                                  \
        ED = edata[ei_];                                        \
        int s_ = ED.x & 0xFFFFF;                                \
        AS = asrc[(long)s_ * 8 + h];                            \
        XL = (float)xlin[(long)s_ * 32 + lc];                   \
    }
#define ECOMP(IDX, ED, AS, XL)                                                         \
    {                                                                                  \
        bool valid_ = (IDX) < deg;                                                     \
        int lt_ = ED.x >> 20;                                                          \
        float t_ = __int_as_float(ED.y);                                               \
        float attc_ = sC[16 + lt_ * 8 + h] + t_ * (t_ > 0.f ? sC[h] : sC[8 + h]);      \
        float lg_ = adst_h + AS + attc_;                                               \
        float w_ = valid_ ? __expf(leakyf(lg_)) : 0.f;                                 \
        float msg_ = XL + t_ * (t_ > 0.f ? linP : linM);                               \
        if (lc < 8) ssum += w_;                                                        \
        float w4_ = dppf<0x124>(w_);                                                   \
        FMAC_DPP_GROUP(acc[0], acc[1], acc[2], acc[3],                                 \
                       acc[4], acc[5], acc[6], acc[7], w_, w4_, msg_);                 \
    }

    if (deg > 0) {
        int deg4 = (deg + 3) & ~3;
        int i = hv;
        int2 e0, e1;
        float a0, x0, a1, x1;
        ELOAD(i, e0, a0, x0);
        ELOAD(i + 2, e1, a1, x1);
        for (; i < deg4; i += 4) {
            int2 f0 = make_int2(0, 0), f1 = make_int2(0, 0);
            float b0 = 0.f, y0 = 0.f, b1v = 0.f, y1 = 0.f;
            if (i + 4 < deg4) {
                ELOAD(i + 4, f0, b0, y0);
                ELOAD(i + 6, f1, b1v, y1);
            }
            ECOMP(i, e0, a0, x0);
            ECOMP(i + 2, e1, a1, x1);
            e0 = f0; a0 = b0; x0 = y0;
            e1 = f1; a1 = b1v; x1 = y1;
        }
    }
#undef ELOAD
#undef ECOMP
    // canonicalize: lanes with (lane&4) have heads 4..7 in acc[0..3] — swap halves
    {
        bool sw = (lane & 4) != 0;
#pragma unroll
        for (int k = 0; k < 4; ++k) {
            float a = acc[k], b = acc[4 + k];
            acc[k] = sw ? b : a;
            acc[4 + k] = sw ? a : b;
        }
    }
#pragma unroll
    for (int hh = 0; hh < 8; ++hh) acc[hh] += __shfl_xor(acc[hh], 32);
    ssum += __shfl_xor(ssum, 32);
    float v[8];
    float s1 = 0.f, s2 = 0.f;
#pragma unroll
    for (int hh = 0; hh < 8; ++hh) {
        float sh = __shfl(ssum, hh);
        float o = acc[hh] / (sh + 1e-16f);
        float vv = o + (float)mres[(long)n * 256 + hh * 32 + lc];
        v[hh] = vv;
        s1 += vv;
        s2 += vv * vv;
    }
#pragma unroll
    for (int d = 1; d < 64; d <<= 1) { s1 += __shfl_xor(s1, d); s2 += __shfl_xor(s2, d); }
    float mu = s1 * (1.f / 512.f);
    float var = s2 * (1.f / 512.f) - mu * mu;
    float rs = rsqrtf(var + 1e-5f);
    if (hv == 0) {
#pragma unroll
        for (int hh = 0; hh < 8; ++hh) {
            int col = hh * 32 + lc;
            float o = (v[hh] - mu) * rs * g1[col] + b1[col];
            m1h[(long)n * 256 + col] = (_Float16)o;
        }
    }
}

// ---------------- FFN1: relu(A[M,256] @ W1T[1024,256]^T + b1) -> fp16 [M,1024] --------
// 128x256 tiles (4 col tiles); XCD remap keeps a row panel's tiles on one XCD.
__global__ __launch_bounds__(256) void k_ffn1(const _Float16* __restrict__ A,
                                              const _Float16* __restrict__ BT,
                                              const float* __restrict__ bias,
                                              _Float16* __restrict__ out,
                                              int M, int nRP) {
    __shared__ _Float16 sA[128 * 64];   // 16KB
    __shared__ _Float16 sB[256 * 64];   // 32KB (reused as epilogue buffer)
    int bid = blockIdx.x;
    int xcd = bid & 7;
    int jj = bid >> 3;
    int ct = jj & 3;
    int rp = xcd + 8 * (jj >> 2);
    if (rp >= nRP) return;
    const int rowBase = rp * 128;
    const int colBase = ct * 256;
    const int tid = threadIdx.x, wid = tid >> 6, lane = tid & 63;
    const int wm = (wid >> 1) * 64, wn2 = (wid & 1) * 128;

    floatx4 acc[4][8];
    floatx4 zz = {0.f, 0.f, 0.f, 0.f};
#pragma unroll
    for (int i = 0; i < 4; ++i)
#pragma unroll
        for (int j = 0; j < 8; ++j) acc[i][j] = zz;

    for (int k0 = 0; k0 < 256; k0 += 64) {
#pragma unroll
        for (int it = 0; it < 4; ++it) {
            int Ci = it * 256 + tid;
            int row = Ci >> 3, ch = Ci & 7;
            int gr = rowBase + row;
            if (gr > M - 1) gr = M - 1;
            gload16(A + (long)gr * 256 + k0 + ((ch ^ (row & 7)) * 8),
                    &sA[(it * 256 + wid * 64) * 8]);
        }
#pragma unroll
        for (int it = 0; it < 8; ++it) {
            int Ci = it * 256 + tid;
            int row = Ci >> 3, ch = Ci & 7;
            gload16(BT + (long)(colBase + row) * 256 + k0 + ((ch ^ (row & 7)) * 8),
                    &sB[(it * 256 + wid * 64) * 8]);
        }
        __syncthreads();
#pragma unroll
        for (int kk = 0; kk < 2; ++kk) {
            half8 af[4], bf[8];
#pragma unroll
            for (int i = 0; i < 4; ++i) {
                int row = wm + i * 16 + (lane & 15);
                int ch = (kk * 4 + (lane >> 4)) ^ (row & 7);
                af[i] = *(const half8*)&sA[row * 64 + ch * 8];
            }
#pragma unroll
            for (int j = 0; j < 8; ++j) {
                int row = wn2 + j * 16 + (lane & 15);
                int ch = (kk * 4 + (lane >> 4)) ^ (row & 7);
                bf[j] = *(const half8*)&sB[row * 64 + ch * 8];
            }
#pragma unroll
            for (int i = 0; i < 4; ++i)
#pragma unroll
                for (int j = 0; j < 8; ++j)
                    acc[i][j] = __builtin_amdgcn_mfma_f32_16x16x32_f16(af[i], bf[j], acc[i][j], 0, 0, 0);
        }
        __syncthreads();
    }
    // epilogue: per-wave transpose via sB (dead after last sync); 16x136 f32 slice/wave
    float* epi = ((float*)sB) + wid * 2176;
#pragma unroll
    for (int i = 0; i < 4; ++i) {
#pragma unroll
        for (int j = 0; j < 8; ++j)
#pragma unroll
            for (int q = 0; q < 4; ++q)
                epi[((lane >> 4) * 4 + q) * 136 + j * 16 + (lane & 15)] = acc[i][j][q];
        __asm__ volatile("s_waitcnt lgkmcnt(0)");
#pragma unroll
        for (int it = 0; it < 8; ++it) {
            int idx = it * 64 + lane;
            int r16 = idx >> 5;
            int c4 = (idx & 31) * 4;
            float4 vv = *(const float4*)&epi[r16 * 136 + c4];
            int grow = rowBase + wm + i * 16 + r16;
            int gcol = colBase + wn2 + c4;
            if (grow < M) {
                float4 bv = *(const float4*)&bias[gcol];
                float o0 = vv.x + bv.x, o1 = vv.y + bv.y, o2 = vv.z + bv.z, o3 = vv.w + bv.w;
                o0 = o0 > 0.f ? o0 : 0.f;
                o1 = o1 > 0.f ? o1 : 0.f;
                o2 = o2 > 0.f ? o2 : 0.f;
                o3 = o3 > 0.f ? o3 : 0.f;
                half4v hv;
                hv[0] = (_Float16)o0; hv[1] = (_Float16)o1;
                hv[2] = (_Float16)o2; hv[3] = (_Float16)o3;
                *(half4v*)&out[(long)grow * 1024 + gcol] = hv;
            }
        }
        __asm__ volatile("s_waitcnt lgkmcnt(0)");
    }
}

// ---------------- FFN2 fused: LN2(A@W2T + b2 + resid) -> fp16 mh (+fp32 out last) -----
__global__ __launch_bounds__(512) void k_ffn2(const _Float16* __restrict__ A,
                                              const _Float16* __restrict__ BT,
                                              const float* __restrict__ bias,
                                              const _Float16* __restrict__ resid,
                                              const float* __restrict__ g2,
                                              const float* __restrict__ b2,
                                              float* __restrict__ outp,
                                              _Float16* __restrict__ outh,
                                              int M, int writeOut) {
    __shared__ _Float16 sA[128 * 64];
    __shared__ _Float16 sB[256 * 64];
    __shared__ float sS1[2][128], sS2[2][128];
    const int rowBase = blockIdx.x * 128;
    const int tid = threadIdx.x, wid = tid >> 6, lane = tid & 63;
    const int wm = (wid >> 1) * 32, wn = (wid & 1) * 128, cg = wid & 1;

    floatx4 acc[2][8];
    floatx4 zz = {0.f, 0.f, 0.f, 0.f};
#pragma unroll
    for (int i = 0; i < 2; ++i)
#pragma unroll
        for (int j = 0; j < 8; ++j) acc[i][j] = zz;

    for (int k0 = 0; k0 < 1024; k0 += 64) {
#pragma unroll
        for (int it = 0; it < 2; ++it) {
            int Ci = it * 512 + tid;
            int row = Ci >> 3, ch = Ci & 7;
            int gr = rowBase + row;
            if (gr > M - 1) gr = M - 1;
            gload16(A + (long)gr * 1024 + k0 + ((ch ^ (row & 7)) * 8),
                    &sA[(it * 512 + wid * 64) * 8]);
        }
#pragma unroll
        for (int it = 0; it < 4; ++it) {
            int Ci = it * 512 + tid;
            int row = Ci >> 3, ch = Ci & 7;
            gload16(BT + (long)row * 1024 + k0 + ((ch ^ (row & 7)) * 8),
                    &sB[(it * 512 + wid * 64) * 8]);
        }
        __syncthreads();
#pragma unroll
        for (int kk = 0; kk < 2; ++kk) {
            half8 af[2], bf[8];
#pragma unroll
            for (int i = 0; i < 2; ++i) {
                int row = wm + i * 16 + (lane & 15);
                int ch = (kk * 4 + (lane >> 4)) ^ (row & 7);
                af[i] = *(const half8*)&sA[row * 64 + ch * 8];
            }
#pragma unroll
            for (int j = 0; j < 8; ++j) {
                int row = wn + j * 16 + (lane & 15);
                int ch = (kk * 4 + (lane >> 4)) ^ (row & 7);
                bf[j] = *(const half8*)&sB[row * 64 + ch * 8];
            }
#pragma unroll
            for (int i = 0; i < 2; ++i)
#pragma unroll
                for (int j = 0; j < 8; ++j)
                    acc[i][j] = __builtin_amdgcn_mfma_f32_16x16x32_f16(af[i], bf[j], acc[i][j], 0, 0, 0);
        }
        __syncthreads();
    }
    // phase 1: bias + residual, row partial sums
#pragma unroll
    for (int i = 0; i < 2; ++i) {
#pragma unroll
        for (int q = 0; q < 4; ++q) {
            int rl = wm + i * 16 + (lane >> 4) * 4 + q;
            long grow = rowBase + rl;
            long gr = grow > M - 1 ? M - 1 : grow;
            float s1 = 0.f, s2 = 0.f;
#pragma unroll
            for (int j = 0; j < 8; ++j) {
                int gcol = wn + j * 16 + (lane & 15);
                float v = acc[i][j][q] + bias[gcol] + (float)resid[gr * 256 + gcol];
                acc[i][j][q] = v;
                s1 += v;
                s2 += v * v;
            }
#pragma unroll
            for (int d = 1; d < 16; d <<= 1) {
                s1 += __shfl_xor(s1, d);
                s2 += __shfl_xor(s2, d);
            }
            if ((lane & 15) == 0) {
                sS1[cg][rl] = s1;
                sS2[cg][rl] = s2;
            }
        }
    }
    __syncthreads();
    // phase 2: normalize + store
#pragma unroll
    for (int i = 0; i < 2; ++i) {
#pragma unroll
        for (int q = 0; q < 4; ++q) {
            int rl = wm + i * 16 + (lane >> 4) * 4 + q;
            long grow = rowBase + rl;
            if (grow < M) {
                float t1 = sS1[0][rl] + sS1[1][rl];
                float t2 = sS2[0][rl] + sS2[1][rl];
                float mu = t1 * (1.f / 256.f);
                float var = t2 * (1.f / 256.f) - mu * mu;
                float rs = rsqrtf(var + 1e-5f);
#pragma unroll
                for (int j = 0; j < 8; ++j) {
                    int gcol = wn + j * 16 + (lane & 15);
                    float o = (acc[i][j][q] - mu) * rs * g2[gcol] + b2[gcol];
                    outh[grow * 256 + gcol] = (_Float16)o;
                    if (writeOut) outp[grow * 256 + gcol] = o;
                }
            }
        }
    }
}

__global__ void k_fail(float* out) {
    if (threadIdx.x == 0 && blockIdx.x == 0) out[0] = 2.0e6f;
}

extern "C" void kernel_launch(void* const* d_in, const int* in_sizes, int n_in,
                              void* d_out, int out_size, void* d_ws, size_t ws_size,
                              hipStream_t stream) {
    const float* x = (const float*)d_in[0];
    const int* ei = (const int*)d_in[1];
    const float* edge_attr = (const float*)d_in[2];
    const int* node_type = (const int*)d_in[3];
    const int* link_type = (const int*)d_in[4];
    const float* Wh = (const float*)d_in[5];
    const float* bh = (const float*)d_in[6];
    const float* Et = (const float*)d_in[7];
    const float* Wea = (const float*)d_in[8];
    const float* Watt = (const float*)d_in[9];
    const float* Wlin = (const float*)d_in[10];
    const float* ffn_w1 = (const float*)d_in[11];
    const float* ffn_b1 = (const float*)d_in[12];
    const float* ffn_w2 = (const float*)d_in[13];
    const float* ffn_b2 = (const float*)d_in[14];
    const float* ln1_g = (const float*)d_in[15];
    const float* ln1_b = (const float*)d_in[16];
    const float* ln2_g = (const float*)d_in[17];
    const float* ln2_b = (const float*)d_in[18];
    const int* srcp = ei;
    const int* dstp = ei + Ee;

    size_t o = 0;
    auto carve = [&](size_t bytes) -> void* {
        void* p = (char*)d_ws + o;
        o += (bytes + 255) & ~(size_t)255;
        return p;
    };
    _Float16* m1h = (_Float16*)carve((size_t)Nn * 256 * 2);
    _Float16* mh = (_Float16*)carve((size_t)Nn * 256 * 2);
    float* adst = (float*)carve((size_t)Nn * 8 * 4);
    float* asrc = (float*)carve((size_t)Nn * 8 * 4);
    _Float16* xlin = (_Float16*)carve((size_t)Nn * 32 * 2);
    int2* edata = (int2*)carve((size_t)Ee * 8);
    int* off = (int*)carve((size_t)(Nn + 1) * 4);
    int* cnt = (int*)carve((size_t)Nn * 4);
    int* cur = (int*)carve((size_t)Nn * 4);
    int* part = (int*)carve(64 * 4);
    int* pref = (int*)carve(64 * 4);
    _Float16* W1T = (_Float16*)carve((size_t)STEPSn * 256 * 1024 * 2);
    _Float16* W2T = (_Float16*)carve((size_t)STEPSn * 256 * 1024 * 2);
    _Float16* Wcmb = (_Float16*)carve(128 * 256 * 2);
    float* bcmb = (float*)carve(128 * 4);
    float* econst = (float*)carve(104 * 4);
    // runtime-sized FFN row chunk: f1h = 2048 B/row
    long remain = (long)ws_size - (long)o;
    long ch = remain / 2048;
    ch = (ch / 128) * 128;
    int CH = ch > Nn ? Nn : (int)ch;
    if (CH < 128) {
        k_fail<<<1, 64, 0, stream>>>((float*)d_out);
        return;
    }
    _Float16* f1h = (_Float16*)carve((size_t)CH * 1024 * 2);
    if (o > ws_size) {
        k_fail<<<1, 64, 0, stream>>>((float*)d_out);
        return;
    }

    hipMemsetAsync(cnt, 0, (size_t)Nn * 4, stream);
    hipMemsetAsync(cur, 0, (size_t)Nn * 4, stream);
    k_count<<<3125, 256, 0, stream>>>(dstp, cnt);
    k_scan1<<<NP, 256, 0, stream>>>(cnt, part);
    k_scan2<<<1, 64, 0, stream>>>(part, pref, off + Nn);
    k_scan3<<<NP, 256, 0, stream>>>(cnt, pref, off);
    k_fill<<<3125, 256, 0, stream>>>(srcp, dstp, edge_attr, link_type, off, cur, edata);
    k_const<<<1, 128, 0, stream>>>(Et, Wea, Watt, Wlin, econst);
    k_comb<<<128, 256, 0, stream>>>(Wh, bh, Watt, Wlin, Wcmb, bcmb);
    k_cvt<<<12500, 256, 0, stream>>>(x, mh);
    k_wtrans<<<STEPSn * 64, 256, 0, stream>>>(ffn_w1, W1T, 256, 1024);
    k_wtrans<<<STEPSn * 64, 256, 0, stream>>>(ffn_w2, W2T, 1024, 256);

    for (int s = 0; s < STEPSn; ++s) {
        k_node_proj2<<<(Nn + 127) / 128, 256, 0, stream>>>(mh, node_type, Wcmb, bcmb,
                                                           adst, asrc, xlin, Nn);
        k_edge_ln1<<<Nn / 4, 256, 0, stream>>>(off, edata, econst, adst, asrc,
                                               xlin, mh, ln1_g + s * 256, ln1_b + s * 256,
                                               m1h);
        int writeOut = (s == STEPSn - 1) ? 1 : 0;
        for (int cs = 0; cs < Nn; cs += CH) {
            int cm = (Nn - cs) < CH ? (Nn - cs) : CH;
            int nRP = (cm + 127) / 128;
            int nRPpad = ((nRP + 7) / 8) * 8;
            k_ffn1<<<nRPpad * 4, 256, 0, stream>>>(
                m1h + (size_t)cs * 256, W1T + (size_t)s * 262144,
                ffn_b1 + s * 1024, f1h, cm, nRP);
            k_ffn2<<<nRP, 512, 0, stream>>>(
                f1h, W2T + (size_t)s * 262144, ffn_b2 + s * 256,
                m1h + (size_t)cs * 256, ln2_g + s * 256, ln2_b + s * 256,
                (float*)d_out + (size_t)cs * 256, mh + (size_t)cs * 256, cm, writeOut);
        }
    }
}

// Round 16
// 1213.381 us; speedup vs baseline: 1.1704x; 1.1704x over previous
//
#include <hip/hip_runtime.h>

#define Nn 50000
#define Ee 800000
#define STEPSn 6
#define NP 49  // ceil(Nn/1024)

typedef _Float16 half8 __attribute__((ext_vector_type(8)));
typedef _Float16 half4v __attribute__((ext_vector_type(4)));
typedef float floatx4 __attribute__((ext_vector_type(4)));

typedef __attribute__((address_space(1))) void gvoid_t;
typedef __attribute__((address_space(3))) void svoid_t;

__device__ __forceinline__ float leakyf(float v) { return v > 0.f ? v : 0.2f * v; }

__device__ __forceinline__ void gload16(const void* g, void* l) {
    __builtin_amdgcn_global_load_lds((const gvoid_t*)g, (svoid_t*)l, 16, 0, 0);
}

// DPP cross-lane read: dst lane i = src lane per CTRL (quad_perm / row_ror)
template <int CTRL>
__device__ __forceinline__ float dppf(float v) {
    return __int_as_float(__builtin_amdgcn_update_dpp(
        0, __float_as_int(v), CTRL, 0xF, 0xF, true));
}

// fused broadcast-accumulate: one asm block, fixed internal order.
// s_nop 1 covers the VALU-write -> DPP-read hazard on W at block entry;
// W4's intrinsic mov_dpp is 5+ instructions before its first DPP read.
#define FMAC_DPP_GROUP(A0, A1, A2, A3, A4, A5, A6, A7, W, W4, MSG)                         \
    asm volatile(                                                                          \
        "s_nop 1\n\t"                                                                      \
        "v_fmac_f32_dpp %0, %8, %10 quad_perm:[0,0,0,0] row_mask:0xf bank_mask:0xf\n\t"    \
        "v_fmac_f32_dpp %1, %8, %10 quad_perm:[1,1,1,1] row_mask:0xf bank_mask:0xf\n\t"    \
        "v_fmac_f32_dpp %2, %8, %10 quad_perm:[2,2,2,2] row_mask:0xf bank_mask:0xf\n\t"    \
        "v_fmac_f32_dpp %3, %8, %10 quad_perm:[3,3,3,3] row_mask:0xf bank_mask:0xf\n\t"    \
        "v_fmac_f32_dpp %4, %9, %10 quad_perm:[0,0,0,0] row_mask:0xf bank_mask:0xf\n\t"    \
        "v_fmac_f32_dpp %5, %9, %10 quad_perm:[1,1,1,1] row_mask:0xf bank_mask:0xf\n\t"    \
        "v_fmac_f32_dpp %6, %9, %10 quad_perm:[2,2,2,2] row_mask:0xf bank_mask:0xf\n\t"    \
        "v_fmac_f32_dpp %7, %9, %10 quad_perm:[3,3,3,3] row_mask:0xf bank_mask:0xf"        \
        : "+v"(A0), "+v"(A1), "+v"(A2), "+v"(A3),                                          \
          "+v"(A4), "+v"(A5), "+v"(A6), "+v"(A7)                                           \
        : "v"(W), "v"(W4), "v"(MSG))

// ---------------- CSR build ----------------
__global__ void k_count(const int* __restrict__ dst, int* __restrict__ cnt) {
    int e = blockIdx.x * 256 + threadIdx.x;
    if (e < Ee) atomicAdd(&cnt[dst[e]], 1);
}

__global__ __launch_bounds__(256) void k_scan1(const int* __restrict__ cnt,
                                               int* __restrict__ part) {
    int b = blockIdx.x, t = threadIdx.x;
    int s = 0;
#pragma unroll
    for (int j = 0; j < 4; ++j) {
        int idx = b * 1024 + j * 256 + t;
        if (idx < Nn) s += cnt[idx];
    }
#pragma unroll
    for (int d = 1; d < 64; d <<= 1) s += __shfl_xor(s, d);
    __shared__ int ws[4];
    if ((t & 63) == 0) ws[t >> 6] = s;
    __syncthreads();
    if (t == 0) part[b] = ws[0] + ws[1] + ws[2] + ws[3];
}

__global__ void k_scan2(const int* __restrict__ part, int* __restrict__ pref,
                        int* __restrict__ offN) {
    int t = threadIdx.x;  // 64
    int v = (t < NP) ? part[t] : 0;
    int p = v;
#pragma unroll
    for (int d = 1; d < 64; d <<= 1) {
        int u = __shfl_up(p, d);
        if (t >= d) p += u;
    }
    if (t < NP) pref[t] = p - v;
    if (t == 63) offN[0] = p;
}

__global__ __launch_bounds__(256) void k_scan3(const int* __restrict__ cnt,
                                               const int* __restrict__ pref,
                                               int* __restrict__ off) {
    __shared__ int wsum[4];
    int b = blockIdx.x, t = threadIdx.x;
    int base = b * 1024;
    int v[4];
    int s = 0;
#pragma unroll
    for (int j = 0; j < 4; ++j) {
        int idx = base + t * 4 + j;
        v[j] = (idx < Nn) ? cnt[idx] : 0;
        s += v[j];
    }
    int lane = t & 63, w = t >> 6;
    int ps = s;
#pragma unroll
    for (int d = 1; d < 64; d <<= 1) {
        int u = __shfl_up(ps, d);
        if (lane >= d) ps += u;
    }
    if (lane == 63) wsum[w] = ps;
    __syncthreads();
    int woff = 0;
    for (int i = 0; i < w; ++i) woff += wsum[i];
    int ex = pref[b] + woff + ps - s;
#pragma unroll
    for (int j = 0; j < 4; ++j) {
        int idx = base + t * 4 + j;
        if (idx < Nn) off[idx] = ex;
        ex += v[j];
    }
}

// fill CSR slots: packed (src | lt<<20, bitcast(edge_attr)) per slot
__global__ void k_fill(const int* __restrict__ src, const int* __restrict__ dst,
                       const float* __restrict__ edge_attr, const int* __restrict__ link_type,
                       const int* __restrict__ off, int* __restrict__ cur,
                       int2* __restrict__ edata) {
    int e = blockIdx.x * 256 + threadIdx.x;
    if (e >= Ee) return;
    int d = dst[e];
    int slot = off[d] + atomicAdd(&cur[d], 1);
    edata[slot] = make_int2(src[e] | (link_type[e] << 20), __float_as_int(edge_attr[e]));
}

// ---------------- tiny per-launch constants ----------------
// C layout: [0:8] attP, [8:16] attM, [16:40] etA (3x8), [40:72] linP, [72:104] linM
__global__ void k_const(const float* __restrict__ Et, const float* __restrict__ Wea,
                        const float* __restrict__ Watt, const float* __restrict__ Wlin,
                        float* __restrict__ C) {
    __shared__ float u[50], v[50];
    int t = threadIdx.x;
    if (t < 50) {
        float w = Wea[t];
        u[t] = w * (w > 0.f ? 1.f : 0.2f);
        v[t] = w * (w < 0.f ? 1.f : 0.2f);
    }
    __syncthreads();
    if (t < 8) {
        float a = 0.f, b = 0.f;
        for (int j = 0; j < 50; ++j) {
            float w = Watt[(74 + j) * 8 + t];
            a += u[j] * w;
            b += v[j] * w;
        }
        C[t] = a;
        C[8 + t] = b;
    } else if (t < 32) {
        int lt = (t - 8) >> 3, h = (t - 8) & 7;
        float a = 0.f;
        for (int j = 0; j < 10; ++j) a += leakyf(Et[lt * 10 + j]) * Watt[(64 + j) * 8 + h];
        C[16 + (t - 8)] = a;
    } else if (t < 64) {
        int c = t - 32;
        float a = 0.f, b = 0.f;
        for (int j = 0; j < 50; ++j) {
            float w = Wlin[(32 + j) * 32 + c];
            a += u[j] * w;
            b += v[j] * w;
        }
        C[40 + c] = a;
        C[72 + c] = b;
    }
}

// ---------------- combined node-proj weights: Wcmb[128][256] fp16, bcmb[96] ----------
__global__ void k_comb(const float* __restrict__ Wh, const float* __restrict__ bh,
                       const float* __restrict__ Watt, const float* __restrict__ Wlin,
                       _Float16* __restrict__ Wcmb, float* __restrict__ bcmb) {
    int n = blockIdx.x;   // 0..127
    int k = threadIdx.x;  // 0..255
    if (n >= 96) {
        Wcmb[n * 256 + k] = (_Float16)0.f;
        return;
    }
    int ty = n / 48, c = n % 48;
    float a = 0.f;
    for (int kk = 0; kk < 32; ++kk) {
        float wsel;
        if (c < 32) wsel = Wlin[kk * 32 + c];
        else if (c < 40) wsel = Watt[kk * 8 + (c - 32)];
        else wsel = Watt[(32 + kk) * 8 + (c - 40)];
        a += Wh[ty * 8192 + k * 32 + kk] * wsel;
    }
    Wcmb[n * 256 + k] = (_Float16)a;
    if (k == 0) {
        float b = 0.f;
        for (int kk = 0; kk < 32; ++kk) {
            float wsel;
            if (c < 32) wsel = Wlin[kk * 32 + c];
            else if (c < 40) wsel = Watt[kk * 8 + (c - 32)];
            else wsel = Watt[(32 + kk) * 8 + (c - 40)];
            b += bh[ty * 32 + kk] * wsel;
        }
        bcmb[n] = b;
    }
}

__global__ void k_cvt(const float* __restrict__ x, _Float16* __restrict__ mh) {
    long i = ((long)blockIdx.x * 256 + threadIdx.x) * 4;
    if (i < (long)Nn * 256) {
        float4 v = *(const float4*)(x + i);
        half4v h;
        h[0] = (_Float16)v.x; h[1] = (_Float16)v.y;
        h[2] = (_Float16)v.z; h[3] = (_Float16)v.w;
        *(half4v*)(mh + i) = h;
    }
}

// ---------------- tiled weight transpose+convert: W [K][NN] fp32 -> WT [NN][K] fp16 ----
__global__ __launch_bounds__(256) void k_wtrans(const float* __restrict__ W,
                                                _Float16* __restrict__ WT,
                                                int K, int NN) {
    __shared__ float tile[64][65];
    int nk = K >> 6, nn = NN >> 6;
    int b = blockIdx.x;
    int s = b / (nk * nn);
    int r = b % (nk * nn);
    int kt = r / nn, nt = r % nn;
    const float* Ws = W + (long)s * K * NN;
    _Float16* WTs = WT + (long)s * K * NN;
    int lrow = threadIdx.x >> 6, lcol = threadIdx.x & 63;
#pragma unroll
    for (int i = 0; i < 16; ++i) {
        int row = i * 4 + lrow;
        tile[row][lcol] = Ws[(long)(kt * 64 + row) * NN + nt * 64 + lcol];
    }
    __syncthreads();
#pragma unroll
    for (int i = 0; i < 16; ++i) {
        int row = i * 4 + lrow;  // n index
        WTs[(long)(nt * 64 + row) * K + kt * 64 + lcol] = (_Float16)tile[lcol][row];
    }
}

// ---------------- node projections via MFMA: mh[M,256] @ Wcmb[128,256]^T ------------
__global__ __launch_bounds__(256) void k_node_proj2(
    const _Float16* __restrict__ mh, const int* __restrict__ node_type,
    const _Float16* __restrict__ Wcmb, const float* __restrict__ bcmb,
    float* __restrict__ adst, float* __restrict__ asrc,
    _Float16* __restrict__ xlin, int M) {
    __shared__ _Float16 sA[128 * 64];
    __shared__ _Float16 sB[128 * 64];
    __shared__ float sEpi[128][100];
    const int rowBase = blockIdx.x * 128;
    const int tid = threadIdx.x, wid = tid >> 6, lane = tid & 63;
    const int wm = (wid >> 1) * 64, wn = (wid & 1) * 64;

    floatx4 acc[4][4];
    floatx4 zz = {0.f, 0.f, 0.f, 0.f};
#pragma unroll
    for (int i = 0; i < 4; ++i)
#pragma unroll
        for (int j = 0; j < 4; ++j) acc[i][j] = zz;

    for (int k0 = 0; k0 < 256; k0 += 64) {
#pragma unroll
        for (int it = 0; it < 4; ++it) {
            int Ci = it * 256 + tid;
            int row = Ci >> 3, ch = Ci & 7;
            int gr = rowBase + row;
            if (gr > M - 1) gr = M - 1;
            gload16(mh + (long)gr * 256 + k0 + ((ch ^ (row & 7)) * 8),
                    &sA[(it * 256 + wid * 64) * 8]);
        }
#pragma unroll
        for (int it = 0; it < 4; ++it) {
            int Ci = it * 256 + tid;
            int row = Ci >> 3, ch = Ci & 7;
            gload16(Wcmb + (long)row * 256 + k0 + ((ch ^ (row & 7)) * 8),
                    &sB[(it * 256 + wid * 64) * 8]);
        }
        __syncthreads();
#pragma unroll
        for (int kk = 0; kk < 2; ++kk) {
            half8 af[4], bf[4];
#pragma unroll
            for (int i = 0; i < 4; ++i) {
                int row = wm + i * 16 + (lane & 15);
                int ch = (kk * 4 + (lane >> 4)) ^ (row & 7);
                af[i] = *(const half8*)&sA[row * 64 + ch * 8];
            }
#pragma unroll
            for (int j = 0; j < 4; ++j) {
                int row = wn + j * 16 + (lane & 15);
                int ch = (kk * 4 + (lane >> 4)) ^ (row & 7);
                bf[j] = *(const half8*)&sB[row * 64 + ch * 8];
            }
#pragma unroll
            for (int i = 0; i < 4; ++i)
#pragma unroll
                for (int j = 0; j < 4; ++j)
                    acc[i][j] = __builtin_amdgcn_mfma_f32_16x16x32_f16(af[i], bf[j], acc[i][j], 0, 0, 0);
        }
        __syncthreads();
    }
#pragma unroll
    for (int i = 0; i < 4; ++i)
#pragma unroll
        for (int j = 0; j < 4; ++j) {
            int col = wn + j * 16 + (lane & 15);
            if (col < 96) {
#pragma unroll
                for (int q = 0; q < 4; ++q)
                    sEpi[wm + i * 16 + (lane >> 4) * 4 + q][col] = acc[i][j][q];
            }
        }
    __syncthreads();
    for (int idx = tid; idx < 128 * 32; idx += 256) {
        int r = idx >> 5, c = idx & 31;
        int gr = rowBase + r;
        if (gr < M) {
            int ty = (node_type[gr] != 0) ? 1 : 0;
            int sc = ty * 48 + c;
            xlin[(long)gr * 32 + c] = (_Float16)(sEpi[r][sc] + bcmb[sc]);
        }
    }
    for (int idx = tid; idx < 128 * 8; idx += 256) {
        int r = idx >> 3, hh = idx & 7;
        int gr = rowBase + r;
        if (gr < M) {
            int ty = (node_type[gr] != 0) ? 1 : 0;
            adst[(long)gr * 8 + hh] = sEpi[r][ty * 48 + 32 + hh] + bcmb[ty * 48 + 32 + hh];
            asrc[(long)gr * 8 + hh] = sEpi[r][ty * 48 + 40 + hh] + bcmb[ty * 48 + 40 + hh];
        }
    }
}

// ---------------- edge aggregation + LN1 (one wave/node; fused fmac_dpp; 4-edge pipe) -
__global__ __launch_bounds__(256) void k_edge_ln1(
    const int* __restrict__ off, const int2* __restrict__ edata,
    const float* __restrict__ C,
    const float* __restrict__ adst, const float* __restrict__ asrc,
    const _Float16* __restrict__ xlin, const _Float16* __restrict__ mres,
    const float* __restrict__ g1, const float* __restrict__ b1,
    _Float16* __restrict__ m1h) {
    __shared__ float sC[104];
    if (threadIdx.x < 104) sC[threadIdx.x] = C[threadIdx.x];
    __syncthreads();
    int n = blockIdx.x * 4 + (threadIdx.x >> 6);
    int lane = threadIdx.x & 63;
    long base = off[n];
    int deg = off[n + 1] - (int)base;
    int h = lane & 7;
    int hv = lane >> 5, lc = lane & 31;
    float adst_h = adst[(long)n * 8 + h];
    float linP = sC[40 + lc], linM = sC[72 + lc];
    float ssum = 0.f;  // lanes sharing the same h hold identical sums; lane hh is read
    float acc[8] = {0.f, 0.f, 0.f, 0.f, 0.f, 0.f, 0.f, 0.f};

#define ELOAD(IDX, ED, AS, XL)                                  \
    {                                                           \
        int ci_ = (IDX) < deg ? (IDX) : deg - 1;                \
        long ei_ = base + ci_;                                  \
        ED = edata[ei_];                                        \
        int s_ = ED.x & 0xFFFFF;                                \
        AS = asrc[(long)s_ * 8 + h];                            \
        XL = (float)xlin[(long)s_ * 32 + lc];                   \
    }
#define ECOMP(IDX, ED, AS, XL)                                                         \
    {                                                                                  \
        bool valid_ = (IDX) < deg;                                                     \
        int lt_ = ED.x >> 20;                                                          \
        float t_ = __int_as_float(ED.y);                                               \
        float attc_ = sC[16 + lt_ * 8 + h] + t_ * (t_ > 0.f ? sC[h] : sC[8 + h]);      \
        float lg_ = adst_h + AS + attc_;                                               \
        float w_ = valid_ ? __expf(leakyf(lg_)) : 0.f;                                 \
        float msg_ = XL + t_ * (t_ > 0.f ? linP : linM);                               \
        ssum += w_;                                                                    \
        float w4_ = dppf<0x124>(w_);                                                   \
        FMAC_DPP_GROUP(acc[0], acc[1], acc[2], acc[3],                                 \
                       acc[4], acc[5], acc[6], acc[7], w_, w4_, msg_);                 \
    }

    if (deg > 0) {
        int deg4 = (deg + 3) & ~3;
        int i = hv;
        int2 e0, e1;
        float a0, x0, a1, x1;
        ELOAD(i, e0, a0, x0);
        ELOAD(i + 2, e1, a1, x1);
        for (; i < deg4; i += 4) {
            int2 f0 = make_int2(0, 0), f1 = make_int2(0, 0);
            float b0 = 0.f, y0 = 0.f, b1v = 0.f, y1 = 0.f;
            if (i + 4 < deg4) {
                ELOAD(i + 4, f0, b0, y0);
                ELOAD(i + 6, f1, b1v, y1);
            }
            ECOMP(i, e0, a0, x0);
            ECOMP(i + 2, e1, a1, x1);
            e0 = f0; a0 = b0; x0 = y0;
            e1 = f1; a1 = b1v; x1 = y1;
        }
    }
#undef ELOAD
#undef ECOMP
    // canonicalize: lanes with (lane&4) have heads 4..7 in acc[0..3] — swap halves
    {
        bool sw = (lane & 4) != 0;
#pragma unroll
        for (int k = 0; k < 4; ++k) {
            float a = acc[k], b = acc[4 + k];
            acc[k] = sw ? b : a;
            acc[4 + k] = sw ? a : b;
        }
    }
#pragma unroll
    for (int hh = 0; hh < 8; ++hh) acc[hh] += __shfl_xor(acc[hh], 32);
    ssum += __shfl_xor(ssum, 32);
    float v[8];
    float s1 = 0.f, s2 = 0.f;
#pragma unroll
    for (int hh = 0; hh < 8; ++hh) {
        float sh = __shfl(ssum, hh);
        float o = acc[hh] / (sh + 1e-16f);
        float vv = o + (float)mres[(long)n * 256 + hh * 32 + lc];
        v[hh] = vv;
        s1 += vv;
        s2 += vv * vv;
    }
#pragma unroll
    for (int d = 1; d < 64; d <<= 1) { s1 += __shfl_xor(s1, d); s2 += __shfl_xor(s2, d); }
    float mu = s1 * (1.f / 512.f);
    float var = s2 * (1.f / 512.f) - mu * mu;
    float rs = rsqrtf(var + 1e-5f);
    if (hv == 0) {
#pragma unroll
        for (int hh = 0; hh < 8; ++hh) {
            int col = hh * 32 + lc;
            float o = (v[hh] - mu) * rs * g1[col] + b1[col];
            m1h[(long)n * 256 + col] = (_Float16)o;
        }
    }
}

// ---------------- FFN1: relu(A[M,256] @ W1T[1024,256]^T + b1) -> fp16 [M,1024] --------
__global__ __launch_bounds__(256) void k_ffn1(const _Float16* __restrict__ A,
                                              const _Float16* __restrict__ BT,
                                              const float* __restrict__ bias,
                                              _Float16* __restrict__ out,
                                              int M, int nRP) {
    __shared__ _Float16 sA[128 * 64];
    __shared__ _Float16 sB[128 * 64];
    __shared__ float sEpi[4][16][68];
    int bid = blockIdx.x;
    int xcd = bid & 7;
    int jj = bid >> 3;
    int ct = jj & 7;
    int rp = xcd + 8 * (jj >> 3);
    if (rp >= nRP) return;
    const int rowBase = rp * 128;
    const int colBase = ct * 128;
    const int tid = threadIdx.x, wid = tid >> 6, lane = tid & 63;
    const int wm = (wid >> 1) * 64, wn = (wid & 1) * 64;

    floatx4 acc[4][4];
    floatx4 zz = {0.f, 0.f, 0.f, 0.f};
#pragma unroll
    for (int i = 0; i < 4; ++i)
#pragma unroll
        for (int j = 0; j < 4; ++j) acc[i][j] = zz;

    for (int k0 = 0; k0 < 256; k0 += 64) {
#pragma unroll
        for (int it = 0; it < 4; ++it) {
            int Ci = it * 256 + tid;
            int row = Ci >> 3, ch = Ci & 7;
            int gr = rowBase + row;
            if (gr > M - 1) gr = M - 1;
            gload16(A + (long)gr * 256 + k0 + ((ch ^ (row & 7)) * 8),
                    &sA[(it * 256 + wid * 64) * 8]);
        }
#pragma unroll
        for (int it = 0; it < 4; ++it) {
            int Ci = it * 256 + tid;
            int row = Ci >> 3, ch = Ci & 7;
            gload16(BT + (long)(colBase + row) * 256 + k0 + ((ch ^ (row & 7)) * 8),
                    &sB[(it * 256 + wid * 64) * 8]);
        }
        __syncthreads();
#pragma unroll
        for (int kk = 0; kk < 2; ++kk) {
            half8 af[4], bf[4];
#pragma unroll
            for (int i = 0; i < 4; ++i) {
                int row = wm + i * 16 + (lane & 15);
                int ch = (kk * 4 + (lane >> 4)) ^ (row & 7);
                af[i] = *(const half8*)&sA[row * 64 + ch * 8];
            }
#pragma unroll
            for (int j = 0; j < 4; ++j) {
                int row = wn + j * 16 + (lane & 15);
                int ch = (kk * 4 + (lane >> 4)) ^ (row & 7);
                bf[j] = *(const half8*)&sB[row * 64 + ch * 8];
            }
#pragma unroll
            for (int i = 0; i < 4; ++i)
#pragma unroll
                for (int j = 0; j < 4; ++j)
                    acc[i][j] = __builtin_amdgcn_mfma_f32_16x16x32_f16(af[i], bf[j], acc[i][j], 0, 0, 0);
        }
        __syncthreads();
    }
    // epilogue: per-wave LDS transpose -> full-line packed fp16 stores
#pragma unroll
    for (int i = 0; i < 4; ++i) {
#pragma unroll
        for (int j = 0; j < 4; ++j)
#pragma unroll
            for (int q = 0; q < 4; ++q)
                sEpi[wid][(lane >> 4) * 4 + q][j * 16 + (lane & 15)] = acc[i][j][q];
        __asm__ volatile("s_waitcnt lgkmcnt(0)");
#pragma unroll
        for (int it = 0; it < 4; ++it) {
            int r16 = it * 4 + (lane >> 4);
            float4 vv = *(const float4*)&sEpi[wid][r16][(lane & 15) * 4];
            int grow = rowBase + wm + i * 16 + r16;
            int gcol = colBase + wn + (lane & 15) * 4;
            if (grow < M) {
                float4 bv = *(const float4*)&bias[gcol];
                float o0 = vv.x + bv.x, o1 = vv.y + bv.y, o2 = vv.z + bv.z, o3 = vv.w + bv.w;
                o0 = o0 > 0.f ? o0 : 0.f;
                o1 = o1 > 0.f ? o1 : 0.f;
                o2 = o2 > 0.f ? o2 : 0.f;
                o3 = o3 > 0.f ? o3 : 0.f;
                half4v hv;
                hv[0] = (_Float16)o0; hv[1] = (_Float16)o1;
                hv[2] = (_Float16)o2; hv[3] = (_Float16)o3;
                *(half4v*)&out[(long)grow * 1024 + gcol] = hv;
            }
        }
        __asm__ volatile("s_waitcnt lgkmcnt(0)");
    }
}

// ---------------- FFN2 fused: LN2(A@W2T + b2 + resid) -> fp16 mh (+fp32 out last) -----
__global__ __launch_bounds__(512) void k_ffn2(const _Float16* __restrict__ A,
                                              const _Float16* __restrict__ BT,
                                              const float* __restrict__ bias,
                                              const _Float16* __restrict__ resid,
                                              const float* __restrict__ g2,
                                              const float* __restrict__ b2,
                                              float* __restrict__ outp,
                                              _Float16* __restrict__ outh,
                                              int M, int writeOut) {
    __shared__ _Float16 sA[128 * 64];
    __shared__ _Float16 sB[256 * 64];
    __shared__ float sS1[2][128], sS2[2][128];
    const int rowBase = blockIdx.x * 128;
    const int tid = threadIdx.x, wid = tid >> 6, lane = tid & 63;
    const int wm = (wid >> 1) * 32, wn = (wid & 1) * 128, cg = wid & 1;

    floatx4 acc[2][8];
    floatx4 zz = {0.f, 0.f, 0.f, 0.f};
#pragma unroll
    for (int i = 0; i < 2; ++i)
#pragma unroll
        for (int j = 0; j < 8; ++j) acc[i][j] = zz;

    for (int k0 = 0; k0 < 1024; k0 += 64) {
#pragma unroll
        for (int it = 0; it < 2; ++it) {
            int Ci = it * 512 + tid;
            int row = Ci >> 3, ch = Ci & 7;
            int gr = rowBase + row;
            if (gr > M - 1) gr = M - 1;
            gload16(A + (long)gr * 1024 + k0 + ((ch ^ (row & 7)) * 8),
                    &sA[(it * 512 + wid * 64) * 8]);
        }
#pragma unroll
        for (int it = 0; it < 4; ++it) {
            int Ci = it * 512 + tid;
            int row = Ci >> 3, ch = Ci & 7;
            gload16(BT + (long)row * 1024 + k0 + ((ch ^ (row & 7)) * 8),
                    &sB[(it * 512 + wid * 64) * 8]);
        }
        __syncthreads();
#pragma unroll
        for (int kk = 0; kk < 2; ++kk) {
            half8 af[2], bf[8];
#pragma unroll
            for (int i = 0; i < 2; ++i) {
                int row = wm + i * 16 + (lane & 15);
                int ch = (kk * 4 + (lane >> 4)) ^ (row & 7);
                af[i] = *(const half8*)&sA[row * 64 + ch * 8];
            }
#pragma unroll
            for (int j = 0; j < 8; ++j) {
                int row = wn + j * 16 + (lane & 15);
                int ch = (kk * 4 + (lane >> 4)) ^ (row & 7);
                bf[j] = *(const half8*)&sB[row * 64 + ch * 8];
            }
#pragma unroll
            for (int i = 0; i < 2; ++i)
#pragma unroll
                for (int j = 0; j < 8; ++j)
                    acc[i][j] = __builtin_amdgcn_mfma_f32_16x16x32_f16(af[i], bf[j], acc[i][j], 0, 0, 0);
        }
        __syncthreads();
    }
    // phase 1: bias + residual, row partial sums
#pragma unroll
    for (int i = 0; i < 2; ++i) {
#pragma unroll
        for (int q = 0; q < 4; ++q) {
            int rl = wm + i * 16 + (lane >> 4) * 4 + q;
            long grow = rowBase + rl;
            long gr = grow > M - 1 ? M - 1 : grow;
            float s1 = 0.f, s2 = 0.f;
#pragma unroll
            for (int j = 0; j < 8; ++j) {
                int gcol = wn + j * 16 + (lane & 15);
                float v = acc[i][j][q] + bias[gcol] + (float)resid[gr * 256 + gcol];
                acc[i][j][q] = v;
                s1 += v;
                s2 += v * v;
            }
#pragma unroll
            for (int d = 1; d < 16; d <<= 1) {
                s1 += __shfl_xor(s1, d);
                s2 += __shfl_xor(s2, d);
            }
            if ((lane & 15) == 0) {
                sS1[cg][rl] = s1;
                sS2[cg][rl] = s2;
            }
        }
    }
    __syncthreads();
    // phase 2: normalize + store
#pragma unroll
    for (int i = 0; i < 2; ++i) {
#pragma unroll
        for (int q = 0; q < 4; ++q) {
            int rl = wm + i * 16 + (lane >> 4) * 4 + q;
            long grow = rowBase + rl;
            if (grow < M) {
                float t1 = sS1[0][rl] + sS1[1][rl];
                float t2 = sS2[0][rl] + sS2[1][rl];
                float mu = t1 * (1.f / 256.f);
                float var = t2 * (1.f / 256.f) - mu * mu;
                float rs = rsqrtf(var + 1e-5f);
#pragma unroll
                for (int j = 0; j < 8; ++j) {
                    int gcol = wn + j * 16 + (lane & 15);
                    float o = (acc[i][j][q] - mu) * rs * g2[gcol] + b2[gcol];
                    outh[grow * 256 + gcol] = (_Float16)o;
                    if (writeOut) outp[grow * 256 + gcol] = o;
                }
            }
        }
    }
}

__global__ void k_fail(float* out) {
    if (threadIdx.x == 0 && blockIdx.x == 0) out[0] = 2.0e6f;
}

extern "C" void kernel_launch(void* const* d_in, const int* in_sizes, int n_in,
                              void* d_out, int out_size, void* d_ws, size_t ws_size,
                              hipStream_t stream) {
    const float* x = (const float*)d_in[0];
    const int* ei = (const int*)d_in[1];
    const float* edge_attr = (const float*)d_in[2];
    const int* node_type = (const int*)d_in[3];
    const int* link_type = (const int*)d_in[4];
    const float* Wh = (const float*)d_in[5];
    const float* bh = (const float*)d_in[6];
    const float* Et = (const float*)d_in[7];
    const float* Wea = (const float*)d_in[8];
    const float* Watt = (const float*)d_in[9];
    const float* Wlin = (const float*)d_in[10];
    const float* ffn_w1 = (const float*)d_in[11];
    const float* ffn_b1 = (const float*)d_in[12];
    const float* ffn_w2 = (const float*)d_in[13];
    const float* ffn_b2 = (const float*)d_in[14];
    const float* ln1_g = (const float*)d_in[15];
    const float* ln1_b = (const float*)d_in[16];
    const float* ln2_g = (const float*)d_in[17];
    const float* ln2_b = (const float*)d_in[18];
    const int* srcp = ei;
    const int* dstp = ei + Ee;

    size_t o = 0;
    auto carve = [&](size_t bytes) -> void* {
        void* p = (char*)d_ws + o;
        o += (bytes + 255) & ~(size_t)255;
        return p;
    };
    _Float16* m1h = (_Float16*)carve((size_t)Nn * 256 * 2);
    _Float16* mh = (_Float16*)carve((size_t)Nn * 256 * 2);
    float* adst = (float*)carve((size_t)Nn * 8 * 4);
    float* asrc = (float*)carve((size_t)Nn * 8 * 4);
    _Float16* xlin = (_Float16*)carve((size_t)Nn * 32 * 2);
    int2* edata = (int2*)carve((size_t)Ee * 8);
    int* off = (int*)carve((size_t)(Nn + 1) * 4);
    int* cnt = (int*)carve((size_t)Nn * 4);
    int* cur = (int*)carve((size_t)Nn * 4);
    int* part = (int*)carve(64 * 4);
    int* pref = (int*)carve(64 * 4);
    _Float16* W1T = (_Float16*)carve((size_t)STEPSn * 256 * 1024 * 2);
    _Float16* W2T = (_Float16*)carve((size_t)STEPSn * 256 * 1024 * 2);
    _Float16* Wcmb = (_Float16*)carve(128 * 256 * 2);
    float* bcmb = (float*)carve(128 * 4);
    float* econst = (float*)carve(104 * 4);
    // runtime-sized FFN row chunk: f1h = 2048 B/row
    long remain = (long)ws_size - (long)o;
    long ch = remain / 2048;
    ch = (ch / 128) * 128;
    int CH = ch > Nn ? Nn : (int)ch;
    if (CH < 128) {
        k_fail<<<1, 64, 0, stream>>>((float*)d_out);
        return;
    }
    _Float16* f1h = (_Float16*)carve((size_t)CH * 1024 * 2);
    if (o > ws_size) {
        k_fail<<<1, 64, 0, stream>>>((float*)d_out);
        return;
    }

    hipMemsetAsync(cnt, 0, (size_t)Nn * 4, stream);
    hipMemsetAsync(cur, 0, (size_t)Nn * 4, stream);
    k_count<<<3125, 256, 0, stream>>>(dstp, cnt);
    k_scan1<<<NP, 256, 0, stream>>>(cnt, part);
    k_scan2<<<1, 64, 0, stream>>>(part, pref, off + Nn);
    k_scan3<<<NP, 256, 0, stream>>>(cnt, pref, off);
    k_fill<<<3125, 256, 0, stream>>>(srcp, dstp, edge_attr, link_type, off, cur, edata);
    k_const<<<1, 128, 0, stream>>>(Et, Wea, Watt, Wlin, econst);
    k_comb<<<128, 256, 0, stream>>>(Wh, bh, Watt, Wlin, Wcmb, bcmb);
    k_cvt<<<12500, 256, 0, stream>>>(x, mh);
    k_wtrans<<<STEPSn * 64, 256, 0, stream>>>(ffn_w1, W1T, 256, 1024);
    k_wtrans<<<STEPSn * 64, 256, 0, stream>>>(ffn_w2, W2T, 1024, 256);

    for (int s = 0; s < STEPSn; ++s) {
        k_node_proj2<<<(Nn + 127) / 128, 256, 0, stream>>>(mh, node_type, Wcmb, bcmb,
                                                           adst, asrc, xlin, Nn);
        k_edge_ln1<<<Nn / 4, 256, 0, stream>>>(off, edata, econst, adst, asrc,
                                               xlin, mh, ln1_g + s * 256, ln1_b + s * 256,
                                               m1h);
        int writeOut = (s == STEPSn - 1) ? 1 : 0;
        for (int cs = 0; cs < Nn; cs += CH) {
            int cm = (Nn - cs) < CH ? (Nn - cs) : CH;
            int nRP = (cm + 127) / 128;
            int nRPpad = ((nRP + 7) / 8) * 8;
            k_ffn1<<<nRPpad * 8, 256, 0, stream>>>(
                m1h + (size_t)cs * 256, W1T + (size_t)s * 262144,
                ffn_b1 + s * 1024, f1h, cm, nRP);
            k_ffn2<<<nRP, 512, 0, stream>>>(
                f1h, W2T + (size_t)s * 262144, ffn_b2 + s * 256,
                m1h + (size_t)cs * 256, ln2_g + s * 256, ln2_b + s * 256,
                (float*)d_out + (size_t)cs * 256, mh + (size_t)cs * 256, cm, writeOut);
        }
    }
}

// Round 17
// 1192.492 us; speedup vs baseline: 1.1909x; 1.0175x over previous
//
#include <hip/hip_runtime.h>

#define Nn 50000
#define Ee 800000
#define STEPSn 6
#define NP 49  // ceil(Nn/1024)

typedef _Float16 half8 __attribute__((ext_vector_type(8)));
typedef _Float16 half4v __attribute__((ext_vector_type(4)));
typedef float floatx4 __attribute__((ext_vector_type(4)));

typedef __attribute__((address_space(1))) void gvoid_t;
typedef __attribute__((address_space(3))) void svoid_t;

__device__ __forceinline__ float leakyf(float v) { return v > 0.f ? v : 0.2f * v; }

__device__ __forceinline__ void gload16(const void* g, void* l) {
    __builtin_amdgcn_global_load_lds((const gvoid_t*)g, (svoid_t*)l, 16, 0, 0);
}

// DPP cross-lane read: dst lane i = src lane per CTRL (quad_perm / row_ror)
template <int CTRL>
__device__ __forceinline__ float dppf(float v) {
    return __int_as_float(__builtin_amdgcn_update_dpp(
        0, __float_as_int(v), CTRL, 0xF, 0xF, true));
}

// fused broadcast-accumulate: one asm block, fixed internal order.
// s_nop 1 covers the VALU-write -> DPP-read hazard on W at block entry;
// W4's intrinsic mov_dpp is 5+ instructions before its first DPP read.
#define FMAC_DPP_GROUP(A0, A1, A2, A3, A4, A5, A6, A7, W, W4, MSG)                         \
    asm volatile(                                                                          \
        "s_nop 1\n\t"                                                                      \
        "v_fmac_f32_dpp %0, %8, %10 quad_perm:[0,0,0,0] row_mask:0xf bank_mask:0xf\n\t"    \
        "v_fmac_f32_dpp %1, %8, %10 quad_perm:[1,1,1,1] row_mask:0xf bank_mask:0xf\n\t"    \
        "v_fmac_f32_dpp %2, %8, %10 quad_perm:[2,2,2,2] row_mask:0xf bank_mask:0xf\n\t"    \
        "v_fmac_f32_dpp %3, %8, %10 quad_perm:[3,3,3,3] row_mask:0xf bank_mask:0xf\n\t"    \
        "v_fmac_f32_dpp %4, %9, %10 quad_perm:[0,0,0,0] row_mask:0xf bank_mask:0xf\n\t"    \
        "v_fmac_f32_dpp %5, %9, %10 quad_perm:[1,1,1,1] row_mask:0xf bank_mask:0xf\n\t"    \
        "v_fmac_f32_dpp %6, %9, %10 quad_perm:[2,2,2,2] row_mask:0xf bank_mask:0xf\n\t"    \
        "v_fmac_f32_dpp %7, %9, %10 quad_perm:[3,3,3,3] row_mask:0xf bank_mask:0xf"        \
        : "+v"(A0), "+v"(A1), "+v"(A2), "+v"(A3),                                          \
          "+v"(A4), "+v"(A5), "+v"(A6), "+v"(A7)                                           \
        : "v"(W), "v"(W4), "v"(MSG))

// ---------------- CSR build ----------------
__global__ void k_count(const int* __restrict__ dst, int* __restrict__ cnt) {
    int e = blockIdx.x * 256 + threadIdx.x;
    if (e < Ee) atomicAdd(&cnt[dst[e]], 1);
}

__global__ __launch_bounds__(256) void k_scan1(const int* __restrict__ cnt,
                                               int* __restrict__ part) {
    int b = blockIdx.x, t = threadIdx.x;
    int s = 0;
#pragma unroll
    for (int j = 0; j < 4; ++j) {
        int idx = b * 1024 + j * 256 + t;
        if (idx < Nn) s += cnt[idx];
    }
#pragma unroll
    for (int d = 1; d < 64; d <<= 1) s += __shfl_xor(s, d);
    __shared__ int ws[4];
    if ((t & 63) == 0) ws[t >> 6] = s;
    __syncthreads();
    if (t == 0) part[b] = ws[0] + ws[1] + ws[2] + ws[3];
}

__global__ void k_scan2(const int* __restrict__ part, int* __restrict__ pref,
                        int* __restrict__ offN) {
    int t = threadIdx.x;  // 64
    int v = (t < NP) ? part[t] : 0;
    int p = v;
#pragma unroll
    for (int d = 1; d < 64; d <<= 1) {
        int u = __shfl_up(p, d);
        if (t >= d) p += u;
    }
    if (t < NP) pref[t] = p - v;
    if (t == 63) offN[0] = p;
}

__global__ __launch_bounds__(256) void k_scan3(const int* __restrict__ cnt,
                                               const int* __restrict__ pref,
                                               int* __restrict__ off) {
    __shared__ int wsum[4];
    int b = blockIdx.x, t = threadIdx.x;
    int base = b * 1024;
    int v[4];
    int s = 0;
#pragma unroll
    for (int j = 0; j < 4; ++j) {
        int idx = base + t * 4 + j;
        v[j] = (idx < Nn) ? cnt[idx] : 0;
        s += v[j];
    }
    int lane = t & 63, w = t >> 6;
    int ps = s;
#pragma unroll
    for (int d = 1; d < 64; d <<= 1) {
        int u = __shfl_up(ps, d);
        if (lane >= d) ps += u;
    }
    if (lane == 63) wsum[w] = ps;
    __syncthreads();
    int woff = 0;
    for (int i = 0; i < w; ++i) woff += wsum[i];
    int ex = pref[b] + woff + ps - s;
#pragma unroll
    for (int j = 0; j < 4; ++j) {
        int idx = base + t * 4 + j;
        if (idx < Nn) off[idx] = ex;
        ex += v[j];
    }
}

// fill CSR slots: packed (src | lt<<20, bitcast(edge_attr)) per slot
__global__ void k_fill(const int* __restrict__ src, const int* __restrict__ dst,
                       const float* __restrict__ edge_attr, const int* __restrict__ link_type,
                       const int* __restrict__ off, int* __restrict__ cur,
                       int2* __restrict__ edata) {
    int e = blockIdx.x * 256 + threadIdx.x;
    if (e >= Ee) return;
    int d = dst[e];
    int slot = off[d] + atomicAdd(&cur[d], 1);
    edata[slot] = make_int2(src[e] | (link_type[e] << 20), __float_as_int(edge_attr[e]));
}

// ---------------- tiny per-launch constants ----------------
// C layout: [0:8] attP, [8:16] attM, [16:40] etA (3x8), [40:72] linP, [72:104] linM
__global__ void k_const(const float* __restrict__ Et, const float* __restrict__ Wea,
                        const float* __restrict__ Watt, const float* __restrict__ Wlin,
                        float* __restrict__ C) {
    __shared__ float u[50], v[50];
    int t = threadIdx.x;
    if (t < 50) {
        float w = Wea[t];
        u[t] = w * (w > 0.f ? 1.f : 0.2f);
        v[t] = w * (w < 0.f ? 1.f : 0.2f);
    }
    __syncthreads();
    if (t < 8) {
        float a = 0.f, b = 0.f;
        for (int j = 0; j < 50; ++j) {
            float w = Watt[(74 + j) * 8 + t];
            a += u[j] * w;
            b += v[j] * w;
        }
        C[t] = a;
        C[8 + t] = b;
    } else if (t < 32) {
        int lt = (t - 8) >> 3, h = (t - 8) & 7;
        float a = 0.f;
        for (int j = 0; j < 10; ++j) a += leakyf(Et[lt * 10 + j]) * Watt[(64 + j) * 8 + h];
        C[16 + (t - 8)] = a;
    } else if (t < 64) {
        int c = t - 32;
        float a = 0.f, b = 0.f;
        for (int j = 0; j < 50; ++j) {
            float w = Wlin[(32 + j) * 32 + c];
            a += u[j] * w;
            b += v[j] * w;
        }
        C[40 + c] = a;
        C[72 + c] = b;
    }
}

// ---------------- combined node-proj weights: Wcmb[128][256] fp16, bcmb[96] ----------
__global__ void k_comb(const float* __restrict__ Wh, const float* __restrict__ bh,
                       const float* __restrict__ Watt, const float* __restrict__ Wlin,
                       _Float16* __restrict__ Wcmb, float* __restrict__ bcmb) {
    int n = blockIdx.x;   // 0..127
    int k = threadIdx.x;  // 0..255
    if (n >= 96) {
        Wcmb[n * 256 + k] = (_Float16)0.f;
        return;
    }
    int ty = n / 48, c = n % 48;
    float a = 0.f;
    for (int kk = 0; kk < 32; ++kk) {
        float wsel;
        if (c < 32) wsel = Wlin[kk * 32 + c];
        else if (c < 40) wsel = Watt[kk * 8 + (c - 32)];
        else wsel = Watt[(32 + kk) * 8 + (c - 40)];
        a += Wh[ty * 8192 + k * 32 + kk] * wsel;
    }
    Wcmb[n * 256 + k] = (_Float16)a;
    if (k == 0) {
        float b = 0.f;
        for (int kk = 0; kk < 32; ++kk) {
            float wsel;
            if (c < 32) wsel = Wlin[kk * 32 + c];
            else if (c < 40) wsel = Watt[kk * 8 + (c - 32)];
            else wsel = Watt[(32 + kk) * 8 + (c - 40)];
            b += bh[ty * 32 + kk] * wsel;
        }
        bcmb[n] = b;
    }
}

__global__ void k_cvt(const float* __restrict__ x, _Float16* __restrict__ mh) {
    long i = ((long)blockIdx.x * 256 + threadIdx.x) * 4;
    if (i < (long)Nn * 256) {
        float4 v = *(const float4*)(x + i);
        half4v h;
        h[0] = (_Float16)v.x; h[1] = (_Float16)v.y;
        h[2] = (_Float16)v.z; h[3] = (_Float16)v.w;
        *(half4v*)(mh + i) = h;
    }
}

// ---------------- tiled weight transpose+convert: W [K][NN] fp32 -> WT [NN][K] fp16 ----
__global__ __launch_bounds__(256) void k_wtrans(const float* __restrict__ W,
                                                _Float16* __restrict__ WT,
                                                int K, int NN) {
    __shared__ float tile[64][65];
    int nk = K >> 6, nn = NN >> 6;
    int b = blockIdx.x;
    int s = b / (nk * nn);
    int r = b % (nk * nn);
    int kt = r / nn, nt = r % nn;
    const float* Ws = W + (long)s * K * NN;
    _Float16* WTs = WT + (long)s * K * NN;
    int lrow = threadIdx.x >> 6, lcol = threadIdx.x & 63;
#pragma unroll
    for (int i = 0; i < 16; ++i) {
        int row = i * 4 + lrow;
        tile[row][lcol] = Ws[(long)(kt * 64 + row) * NN + nt * 64 + lcol];
    }
    __syncthreads();
#pragma unroll
    for (int i = 0; i < 16; ++i) {
        int row = i * 4 + lrow;  // n index
        WTs[(long)(nt * 64 + row) * K + kt * 64 + lcol] = (_Float16)tile[lcol][row];
    }
}

// ---------------- node projections via MFMA: mh[M,256] @ Wcmb[128,256]^T ------------
__global__ __launch_bounds__(256) void k_node_proj2(
    const _Float16* __restrict__ mh, const int* __restrict__ node_type,
    const _Float16* __restrict__ Wcmb, const float* __restrict__ bcmb,
    float* __restrict__ adst, float* __restrict__ asrc,
    _Float16* __restrict__ xlin, int M) {
    __shared__ _Float16 sA[128 * 64];
    __shared__ _Float16 sB[128 * 64];
    __shared__ float sEpi[128][100];
    const int rowBase = blockIdx.x * 128;
    const int tid = threadIdx.x, wid = tid >> 6, lane = tid & 63;
    const int wm = (wid >> 1) * 64, wn = (wid & 1) * 64;

    floatx4 acc[4][4];
    floatx4 zz = {0.f, 0.f, 0.f, 0.f};
#pragma unroll
    for (int i = 0; i < 4; ++i)
#pragma unroll
        for (int j = 0; j < 4; ++j) acc[i][j] = zz;

    for (int k0 = 0; k0 < 256; k0 += 64) {
#pragma unroll
        for (int it = 0; it < 4; ++it) {
            int Ci = it * 256 + tid;
            int row = Ci >> 3, ch = Ci & 7;
            int gr = rowBase + row;
            if (gr > M - 1) gr = M - 1;
            gload16(mh + (long)gr * 256 + k0 + ((ch ^ (row & 7)) * 8),
                    &sA[(it * 256 + wid * 64) * 8]);
        }
#pragma unroll
        for (int it = 0; it < 4; ++it) {
            int Ci = it * 256 + tid;
            int row = Ci >> 3, ch = Ci & 7;
            gload16(Wcmb + (long)row * 256 + k0 + ((ch ^ (row & 7)) * 8),
                    &sB[(it * 256 + wid * 64) * 8]);
        }
        __syncthreads();
#pragma unroll
        for (int kk = 0; kk < 2; ++kk) {
            half8 af[4], bf[4];
#pragma unroll
            for (int i = 0; i < 4; ++i) {
                int row = wm + i * 16 + (lane & 15);
                int ch = (kk * 4 + (lane >> 4)) ^ (row & 7);
                af[i] = *(const half8*)&sA[row * 64 + ch * 8];
            }
#pragma unroll
            for (int j = 0; j < 4; ++j) {
                int row = wn + j * 16 + (lane & 15);
                int ch = (kk * 4 + (lane >> 4)) ^ (row & 7);
                bf[j] = *(const half8*)&sB[row * 64 + ch * 8];
            }
#pragma unroll
            for (int i = 0; i < 4; ++i)
#pragma unroll
                for (int j = 0; j < 4; ++j)
                    acc[i][j] = __builtin_amdgcn_mfma_f32_16x16x32_f16(af[i], bf[j], acc[i][j], 0, 0, 0);
        }
        __syncthreads();
    }
#pragma unroll
    for (int i = 0; i < 4; ++i)
#pragma unroll
        for (int j = 0; j < 4; ++j) {
            int col = wn + j * 16 + (lane & 15);
            if (col < 96) {
#pragma unroll
                for (int q = 0; q < 4; ++q)
                    sEpi[wm + i * 16 + (lane >> 4) * 4 + q][col] = acc[i][j][q];
            }
        }
    __syncthreads();
    for (int idx = tid; idx < 128 * 32; idx += 256) {
        int r = idx >> 5, c = idx & 31;
        int gr = rowBase + r;
        if (gr < M) {
            int ty = (node_type[gr] != 0) ? 1 : 0;
            int sc = ty * 48 + c;
            xlin[(long)gr * 32 + c] = (_Float16)(sEpi[r][sc] + bcmb[sc]);
        }
    }
    for (int idx = tid; idx < 128 * 8; idx += 256) {
        int r = idx >> 3, hh = idx & 7;
        int gr = rowBase + r;
        if (gr < M) {
            int ty = (node_type[gr] != 0) ? 1 : 0;
            adst[(long)gr * 8 + hh] = sEpi[r][ty * 48 + 32 + hh] + bcmb[ty * 48 + 32 + hh];
            asrc[(long)gr * 8 + hh] = sEpi[r][ty * 48 + 40 + hh] + bcmb[ty * 48 + 40 + hh];
        }
    }
}

// ---------------- edge aggregation + LN1 (decoupled prefetch: edata 8 ahead) ----------
__global__ __launch_bounds__(256) void k_edge_ln1(
    const int* __restrict__ off, const int2* __restrict__ edata,
    const float* __restrict__ C,
    const float* __restrict__ adst, const float* __restrict__ asrc,
    const _Float16* __restrict__ xlin, const _Float16* __restrict__ mres,
    const float* __restrict__ g1, const float* __restrict__ b1,
    _Float16* __restrict__ m1h) {
    __shared__ float sC[104];
    if (threadIdx.x < 104) sC[threadIdx.x] = C[threadIdx.x];
    __syncthreads();
    int n = blockIdx.x * 4 + (threadIdx.x >> 6);
    int lane = threadIdx.x & 63;
    long base = off[n];
    int deg = off[n + 1] - (int)base;
    int h = lane & 7;
    int hv = lane >> 5, lc = lane & 31;
    float adst_h = adst[(long)n * 8 + h];
    float linP = sC[40 + lc], linM = sC[72 + lc];
    float ssum = 0.f;
    float acc[8] = {0.f, 0.f, 0.f, 0.f, 0.f, 0.f, 0.f, 0.f};

#define CLMP(IDX) ((IDX) < deg ? (IDX) : deg - 1)
#define GATH(ED, AS, XL)                                        \
    {                                                           \
        int s_ = ED.x & 0xFFFFF;                                \
        AS = asrc[(long)s_ * 8 + h];                            \
        XL = (float)xlin[(long)s_ * 32 + lc];                   \
    }
#define ECOMP(IDX, ED, AS, XL)                                                         \
    {                                                                                  \
        bool valid_ = (IDX) < deg;                                                     \
        int lt_ = ED.x >> 20;                                                          \
        float t_ = __int_as_float(ED.y);                                               \
        float attc_ = sC[16 + lt_ * 8 + h] + t_ * (t_ > 0.f ? sC[h] : sC[8 + h]);      \
        float lg_ = adst_h + AS + attc_;                                               \
        float w_ = valid_ ? __expf(leakyf(lg_)) : 0.f;                                 \
        float msg_ = XL + t_ * (t_ > 0.f ? linP : linM);                               \
        ssum += w_;                                                                    \
        float w4_ = dppf<0x124>(w_);                                                   \
        FMAC_DPP_GROUP(acc[0], acc[1], acc[2], acc[3],                                 \
                       acc[4], acc[5], acc[6], acc[7], w_, w4_, msg_);                 \
    }

    if (deg > 0) {
        int deg4 = (deg + 3) & ~3;
        // edata 4-entry (8-edge) pipeline; dependent gathers issued from resident edata
        int2 ed0 = edata[base + CLMP(hv)];
        int2 ed1 = edata[base + CLMP(hv + 2)];
        int2 ed2 = edata[base + CLMP(hv + 4)];
        int2 ed3 = edata[base + CLMP(hv + 6)];
        float a0, x0, a1, x1;
        GATH(ed0, a0, x0);
        GATH(ed1, a1, x1);
        for (int i = hv; i < deg4; i += 4) {
            int2 nd0 = edata[base + CLMP(i + 8)];
            int2 nd1 = edata[base + CLMP(i + 10)];
            float na0, nx0, na1, nx1;
            GATH(ed2, na0, nx0);
            GATH(ed3, na1, nx1);
            ECOMP(i, ed0, a0, x0);
            ECOMP(i + 2, ed1, a1, x1);
            ed0 = ed2; ed1 = ed3; ed2 = nd0; ed3 = nd1;
            a0 = na0; x0 = nx0; a1 = na1; x1 = nx1;
        }
    }
#undef CLMP
#undef GATH
#undef ECOMP
    // canonicalize: lanes with (lane&4) have heads 4..7 in acc[0..3] — swap halves
    {
        bool sw = (lane & 4) != 0;
#pragma unroll
        for (int k = 0; k < 4; ++k) {
            float a = acc[k], b = acc[4 + k];
            acc[k] = sw ? b : a;
            acc[4 + k] = sw ? a : b;
        }
    }
#pragma unroll
    for (int hh = 0; hh < 8; ++hh) acc[hh] += __shfl_xor(acc[hh], 32);
    ssum += __shfl_xor(ssum, 32);
    float v[8];
    float s1 = 0.f, s2 = 0.f;
#pragma unroll
    for (int hh = 0; hh < 8; ++hh) {
        float sh = __shfl(ssum, hh);
        float o = acc[hh] / (sh + 1e-16f);
        float vv = o + (float)mres[(long)n * 256 + hh * 32 + lc];
        v[hh] = vv;
        s1 += vv;
        s2 += vv * vv;
    }
#pragma unroll
    for (int d = 1; d < 64; d <<= 1) { s1 += __shfl_xor(s1, d); s2 += __shfl_xor(s2, d); }
    float mu = s1 * (1.f / 512.f);
    float var = s2 * (1.f / 512.f) - mu * mu;
    float rs = rsqrtf(var + 1e-5f);
    if (hv == 0) {
#pragma unroll
        for (int hh = 0; hh < 8; ++hh) {
            int col = hh * 32 + lc;
            float o = (v[hh] - mu) * rs * g1[col] + b1[col];
            m1h[(long)n * 256 + col] = (_Float16)o;
        }
    }
}

// ---------------- FFN1: relu(A[M,256] @ W1T[1024,256]^T + b1) -> fp16 [M,1024] --------
__global__ __launch_bounds__(256) void k_ffn1(const _Float16* __restrict__ A,
                                              const _Float16* __restrict__ BT,
                                              const float* __restrict__ bias,
                                              _Float16* __restrict__ out,
                                              int M, int nRP) {
    __shared__ _Float16 sA[128 * 64];
    __shared__ _Float16 sB[128 * 64];
    __shared__ float sEpi[4][16][68];
    int bid = blockIdx.x;
    int xcd = bid & 7;
    int jj = bid >> 3;
    int ct = jj & 7;
    int rp = xcd + 8 * (jj >> 3);
    if (rp >= nRP) return;
    const int rowBase = rp * 128;
    const int colBase = ct * 128;
    const int tid = threadIdx.x, wid = tid >> 6, lane = tid & 63;
    const int wm = (wid >> 1) * 64, wn = (wid & 1) * 64;

    floatx4 acc[4][4];
    floatx4 zz = {0.f, 0.f, 0.f, 0.f};
#pragma unroll
    for (int i = 0; i < 4; ++i)
#pragma unroll
        for (int j = 0; j < 4; ++j) acc[i][j] = zz;

    for (int k0 = 0; k0 < 256; k0 += 64) {
#pragma unroll
        for (int it = 0; it < 4; ++it) {
            int Ci = it * 256 + tid;
            int row = Ci >> 3, ch = Ci & 7;
            int gr = rowBase + row;
            if (gr > M - 1) gr = M - 1;
            gload16(A + (long)gr * 256 + k0 + ((ch ^ (row & 7)) * 8),
                    &sA[(it * 256 + wid * 64) * 8]);
        }
#pragma unroll
        for (int it = 0; it < 4; ++it) {
            int Ci = it * 256 + tid;
            int row = Ci >> 3, ch = Ci & 7;
            gload16(BT + (long)(colBase + row) * 256 + k0 + ((ch ^ (row & 7)) * 8),
                    &sB[(it * 256 + wid * 64) * 8]);
        }
        __syncthreads();
#pragma unroll
        for (int kk = 0; kk < 2; ++kk) {
            half8 af[4], bf[4];
#pragma unroll
            for (int i = 0; i < 4; ++i) {
                int row = wm + i * 16 + (lane & 15);
                int ch = (kk * 4 + (lane >> 4)) ^ (row & 7);
                af[i] = *(const half8*)&sA[row * 64 + ch * 8];
            }
#pragma unroll
            for (int j = 0; j < 4; ++j) {
                int row = wn + j * 16 + (lane & 15);
                int ch = (kk * 4 + (lane >> 4)) ^ (row & 7);
                bf[j] = *(const half8*)&sB[row * 64 + ch * 8];
            }
#pragma unroll
            for (int i = 0; i < 4; ++i)
#pragma unroll
                for (int j = 0; j < 4; ++j)
                    acc[i][j] = __builtin_amdgcn_mfma_f32_16x16x32_f16(af[i], bf[j], acc[i][j], 0, 0, 0);
        }
        __syncthreads();
    }
    // epilogue: per-wave LDS transpose -> full-line packed fp16 stores
#pragma unroll
    for (int i = 0; i < 4; ++i) {
#pragma unroll
        for (int j = 0; j < 4; ++j)
#pragma unroll
            for (int q = 0; q < 4; ++q)
                sEpi[wid][(lane >> 4) * 4 + q][j * 16 + (lane & 15)] = acc[i][j][q];
        __asm__ volatile("s_waitcnt lgkmcnt(0)");
#pragma unroll
        for (int it = 0; it < 4; ++it) {
            int r16 = it * 4 + (lane >> 4);
            float4 vv = *(const float4*)&sEpi[wid][r16][(lane & 15) * 4];
            int grow = rowBase + wm + i * 16 + r16;
            int gcol = colBase + wn + (lane & 15) * 4;
            if (grow < M) {
                float4 bv = *(const float4*)&bias[gcol];
                float o0 = vv.x + bv.x, o1 = vv.y + bv.y, o2 = vv.z + bv.z, o3 = vv.w + bv.w;
                o0 = o0 > 0.f ? o0 : 0.f;
                o1 = o1 > 0.f ? o1 : 0.f;
                o2 = o2 > 0.f ? o2 : 0.f;
                o3 = o3 > 0.f ? o3 : 0.f;
                half4v hv;
                hv[0] = (_Float16)o0; hv[1] = (_Float16)o1;
                hv[2] = (_Float16)o2; hv[3] = (_Float16)o3;
                *(half4v*)&out[(long)grow * 1024 + gcol] = hv;
            }
        }
        __asm__ volatile("s_waitcnt lgkmcnt(0)");
    }
}

// ---------------- FFN2 fused: LN2(A@W2T + b2 + resid) -> fp16 mh (+fp32 out last) -----
__global__ __launch_bounds__(512) void k_ffn2(const _Float16* __restrict__ A,
                                              const _Float16* __restrict__ BT,
                                              const float* __restrict__ bias,
                                              const _Float16* __restrict__ resid,
                                              const float* __restrict__ g2,
                                              const float* __restrict__ b2,
                                              float* __restrict__ outp,
                                              _Float16* __restrict__ outh,
                                              int M, int writeOut) {
    __shared__ _Float16 sA[128 * 64];
    __shared__ _Float16 sB[256 * 64];
    __shared__ float sS1[2][128], sS2[2][128];
    const int rowBase = blockIdx.x * 128;
    const int tid = threadIdx.x, wid = tid >> 6, lane = tid & 63;
    const int wm = (wid >> 1) * 32, wn = (wid & 1) * 128, cg = wid & 1;

    floatx4 acc[2][8];
    floatx4 zz = {0.f, 0.f, 0.f, 0.f};
#pragma unroll
    for (int i = 0; i < 2; ++i)
#pragma unroll
        for (int j = 0; j < 8; ++j) acc[i][j] = zz;

    for (int k0 = 0; k0 < 1024; k0 += 64) {
#pragma unroll
        for (int it = 0; it < 2; ++it) {
            int Ci = it * 512 + tid;
            int row = Ci >> 3, ch = Ci & 7;
            int gr = rowBase + row;
            if (gr > M - 1) gr = M - 1;
            gload16(A + (long)gr * 1024 + k0 + ((ch ^ (row & 7)) * 8),
                    &sA[(it * 512 + wid * 64) * 8]);
        }
#pragma unroll
        for (int it = 0; it < 4; ++it) {
            int Ci = it * 512 + tid;
            int row = Ci >> 3, ch = Ci & 7;
            gload16(BT + (long)row * 1024 + k0 + ((ch ^ (row & 7)) * 8),
                    &sB[(it * 512 + wid * 64) * 8]);
        }
        __syncthreads();
#pragma unroll
        for (int kk = 0; kk < 2; ++kk) {
            half8 af[2], bf[8];
#pragma unroll
            for (int i = 0; i < 2; ++i) {
                int row = wm + i * 16 + (lane & 15);
                int ch = (kk * 4 + (lane >> 4)) ^ (row & 7);
                af[i] = *(const half8*)&sA[row * 64 + ch * 8];
            }
#pragma unroll
            for (int j = 0; j < 8; ++j) {
                int row = wn + j * 16 + (lane & 15);
                int ch = (kk * 4 + (lane >> 4)) ^ (row & 7);
                bf[j] = *(const half8*)&sB[row * 64 + ch * 8];
            }
#pragma unroll
            for (int i = 0; i < 2; ++i)
#pragma unroll
                for (int j = 0; j < 8; ++j)
                    acc[i][j] = __builtin_amdgcn_mfma_f32_16x16x32_f16(af[i], bf[j], acc[i][j], 0, 0, 0);
        }
        __syncthreads();
    }
    // phase 1: bias + residual, row partial sums
#pragma unroll
    for (int i = 0; i < 2; ++i) {
#pragma unroll
        for (int q = 0; q < 4; ++q) {
            int rl = wm + i * 16 + (lane >> 4) * 4 + q;
            long grow = rowBase + rl;
            long gr = grow > M - 1 ? M - 1 : grow;
            float s1 = 0.f, s2 = 0.f;
#pragma unroll
            for (int j = 0; j < 8; ++j) {
                int gcol = wn + j * 16 + (lane & 15);
                float v = acc[i][j][q] + bias[gcol] + (float)resid[gr * 256 + gcol];
                acc[i][j][q] = v;
                s1 += v;
                s2 += v * v;
            }
#pragma unroll
            for (int d = 1; d < 16; d <<= 1) {
                s1 += __shfl_xor(s1, d);
                s2 += __shfl_xor(s2, d);
            }
            if ((lane & 15) == 0) {
                sS1[cg][rl] = s1;
                sS2[cg][rl] = s2;
            }
        }
    }
    __syncthreads();
    // phase 2: normalize + store
#pragma unroll
    for (int i = 0; i < 2; ++i) {
#pragma unroll
        for (int q = 0; q < 4; ++q) {
            int rl = wm + i * 16 + (lane >> 4) * 4 + q;
            long grow = rowBase + rl;
            if (grow < M) {
                float t1 = sS1[0][rl] + sS1[1][rl];
                float t2 = sS2[0][rl] + sS2[1][rl];
                float mu = t1 * (1.f / 256.f);
                float var = t2 * (1.f / 256.f) - mu * mu;
                float rs = rsqrtf(var + 1e-5f);
#pragma unroll
                for (int j = 0; j < 8; ++j) {
                    int gcol = wn + j * 16 + (lane & 15);
                    float o = (acc[i][j][q] - mu) * rs * g2[gcol] + b2[gcol];
                    outh[grow * 256 + gcol] = (_Float16)o;
                    if (writeOut) outp[grow * 256 + gcol] = o;
                }
            }
        }
    }
}

__global__ void k_fail(float* out) {
    if (threadIdx.x == 0 && blockIdx.x == 0) out[0] = 2.0e6f;
}

extern "C" void kernel_launch(void* const* d_in, const int* in_sizes, int n_in,
                              void* d_out, int out_size, void* d_ws, size_t ws_size,
                              hipStream_t stream) {
    const float* x = (const float*)d_in[0];
    const int* ei = (const int*)d_in[1];
    const float* edge_attr = (const float*)d_in[2];
    const int* node_type = (const int*)d_in[3];
    const int* link_type = (const int*)d_in[4];
    const float* Wh = (const float*)d_in[5];
    const float* bh = (const float*)d_in[6];
    const float* Et = (const float*)d_in[7];
    const float* Wea = (const float*)d_in[8];
    const float* Watt = (const float*)d_in[9];
    const float* Wlin = (const float*)d_in[10];
    const float* ffn_w1 = (const float*)d_in[11];
    const float* ffn_b1 = (const float*)d_in[12];
    const float* ffn_w2 = (const float*)d_in[13];
    const float* ffn_b2 = (const float*)d_in[14];
    const float* ln1_g = (const float*)d_in[15];
    const float* ln1_b = (const float*)d_in[16];
    const float* ln2_g = (const float*)d_in[17];
    const float* ln2_b = (const float*)d_in[18];
    const int* srcp = ei;
    const int* dstp = ei + Ee;

    size_t o = 0;
    auto carve = [&](size_t bytes) -> void* {
        void* p = (char*)d_ws + o;
        o += (bytes + 255) & ~(size_t)255;
        return p;
    };
    _Float16* m1h = (_Float16*)carve((size_t)Nn * 256 * 2);
    _Float16* mh = (_Float16*)carve((size_t)Nn * 256 * 2);
    float* adst = (float*)carve((size_t)Nn * 8 * 4);
    float* asrc = (float*)carve((size_t)Nn * 8 * 4);
    _Float16* xlin = (_Float16*)carve((size_t)Nn * 32 * 2);
    int2* edata = (int2*)carve((size_t)Ee * 8);
    int* off = (int*)carve((size_t)(Nn + 1) * 4);
    int* cnt = (int*)carve((size_t)Nn * 4);
    int* cur = (int*)carve((size_t)Nn * 4);
    int* part = (int*)carve(64 * 4);
    int* pref = (int*)carve(64 * 4);
    _Float16* W1T = (_Float16*)carve((size_t)STEPSn * 256 * 1024 * 2);
    _Float16* W2T = (_Float16*)carve((size_t)STEPSn * 256 * 1024 * 2);
    _Float16* Wcmb = (_Float16*)carve(128 * 256 * 2);
    float* bcmb = (float*)carve(128 * 4);
    float* econst = (float*)carve(104 * 4);
    // runtime-sized FFN row chunk: f1h = 2048 B/row
    long remain = (long)ws_size - (long)o;
    long ch = remain / 2048;
    ch = (ch / 128) * 128;
    int CH = ch > Nn ? Nn : (int)ch;
    if (CH < 128) {
        k_fail<<<1, 64, 0, stream>>>((float*)d_out);
        return;
    }
    _Float16* f1h = (_Float16*)carve((size_t)CH * 1024 * 2);
    if (o > ws_size) {
        k_fail<<<1, 64, 0, stream>>>((float*)d_out);
        return;
    }

    hipMemsetAsync(cnt, 0, (size_t)Nn * 4, stream);
    hipMemsetAsync(cur, 0, (size_t)Nn * 4, stream);
    k_count<<<3125, 256, 0, stream>>>(dstp, cnt);
    k_scan1<<<NP, 256, 0, stream>>>(cnt, part);
    k_scan2<<<1, 64, 0, stream>>>(part, pref, off + Nn);
    k_scan3<<<NP, 256, 0, stream>>>(cnt, pref, off);
    k_fill<<<3125, 256, 0, stream>>>(srcp, dstp, edge_attr, link_type, off, cur, edata);
    k_const<<<1, 128, 0, stream>>>(Et, Wea, Watt, Wlin, econst);
    k_comb<<<128, 256, 0, stream>>>(Wh, bh, Watt, Wlin, Wcmb, bcmb);
    k_cvt<<<12500, 256, 0, stream>>>(x, mh);
    k_wtrans<<<STEPSn * 64, 256, 0, stream>>>(ffn_w1, W1T, 256, 1024);
    k_wtrans<<<STEPSn * 64, 256, 0, stream>>>(ffn_w2, W2T, 1024, 256);

    for (int s = 0; s < STEPSn; ++s) {
        k_node_proj2<<<(Nn + 127) / 128, 256, 0, stream>>>(mh, node_type, Wcmb, bcmb,
                                                           adst, asrc, xlin, Nn);
        k_edge_ln1<<<Nn / 4, 256, 0, stream>>>(off, edata, econst, adst, asrc,
                                               xlin, mh, ln1_g + s * 256, ln1_b + s * 256,
                                               m1h);
        int writeOut = (s == STEPSn - 1) ? 1 : 0;
        for (int cs = 0; cs < Nn; cs += CH) {
            int cm = (Nn - cs) < CH ? (Nn - cs) : CH;
            int nRP = (cm + 127) / 128;
            int nRPpad = ((nRP + 7) / 8) * 8;
            k_ffn1<<<nRPpad * 8, 256, 0, stream>>>(
                m1h + (size_t)cs * 256, W1T + (size_t)s * 262144,
                ffn_b1 + s * 1024, f1h, cm, nRP);
            k_ffn2<<<nRP, 512, 0, stream>>>(
                f1h, W2T + (size_t)s * 262144, ffn_b2 + s * 256,
                m1h + (size_t)cs * 256, ln2_g + s * 256, ln2_b + s * 256,
                (float*)d_out + (size_t)cs * 256, mh + (size_t)cs * 256, cm, writeOut);
        }
    }
}